// Round 2
// baseline (558.839 us; speedup 1.0000x reference)
//
#include <hip/hip_runtime.h>
#include <math.h>

#define NUM_ITER 10
#define Z_MIN 0.1f

// Branchless f32 LDL^T solve of 4x4 SPD system. t = upper-tri packed
// (00,01,02,03,11,12,13,22,23,33), solves A x = b.
__device__ inline void solve4_spd(const float t[10], const float b[4], float x[4]) {
    const float d0 = t[0];
    const float i0 = 1.0f / d0;
    const float L10 = t[1] * i0, L20 = t[2] * i0, L30 = t[3] * i0;
    const float d1 = t[4] - L10 * t[1];
    const float i1 = 1.0f / d1;
    const float L21 = (t[5] - L20 * t[1]) * i1;
    const float L31 = (t[6] - L30 * t[1]) * i1;
    const float d2 = t[7] - L20 * t[2] - L21 * L21 * d1;
    const float i2 = 1.0f / d2;
    const float L32 = (t[8] - L30 * t[2] - L31 * L21 * d1) * i2;
    const float d3 = t[9] - L30 * t[3] - L31 * L31 * d1 - L32 * L32 * d2;
    const float i3 = 1.0f / d3;
    const float y0 = b[0];
    const float y1 = b[1] - L10 * y0;
    const float y2 = b[2] - L20 * y0 - L21 * y1;
    const float y3 = b[3] - L30 * y0 - L31 * y1 - L32 * y2;
    const float z0 = y0 * i0, z1 = y1 * i1, z2 = y2 * i2, z3 = y3 * i3;
    x[3] = z3;
    x[2] = z2 - L32 * z3;
    x[1] = z1 - L21 * x[2] - L31 * x[3];
    x[0] = z0 - L10 * x[1] - L20 * x[2] - L30 * x[3];
}

// One wave (64 lanes) per batch item; 4 independent waves per 256-block.
// PPL points per lane. EXACT: N == 64*PPL and PPL%4==0 -> float4 loads of
// contiguous per-lane point chunks. No LDS, no __syncthreads anywhere.
template <int PPL, bool EXACT>
__global__ __launch_bounds__(256, 4) void lm_kernel(
    const float* __restrict__ x3d, const float* __restrict__ x2d,
    const float* __restrict__ w2d, const float* __restrict__ pose_init,
    const float* __restrict__ K, float* __restrict__ out, int B, int N)
{
    const int wave = threadIdx.x >> 6;
    const int lane = threadIdx.x & 63;
    const int item = blockIdx.x * 4 + wave;
    if (item >= B) return;  // wave-uniform

    // ---- load point data into registers (read exactly once) ----
    float f3[3 * PPL], f2[2 * PPL], fw[2 * PPL];
    const float* x3b = x3d + (size_t)item * N * 3;
    const float* x2b = x2d + (size_t)item * N * 2;
    const float* w2b = w2d + (size_t)item * N * 2;
    if (EXACT) {
        // lane owns contiguous points [PPL*lane, PPL*lane+PPL)
        const float4* p3 = reinterpret_cast<const float4*>(x3b) + lane * (3 * PPL / 4);
        const float4* p2 = reinterpret_cast<const float4*>(x2b) + lane * (2 * PPL / 4);
        const float4* pw = reinterpret_cast<const float4*>(w2b) + lane * (2 * PPL / 4);
        float4* d3 = reinterpret_cast<float4*>(f3);
        float4* d2 = reinterpret_cast<float4*>(f2);
        float4* dw = reinterpret_cast<float4*>(fw);
#pragma unroll
        for (int i = 0; i < 3 * PPL / 4; ++i) d3[i] = p3[i];
#pragma unroll
        for (int i = 0; i < 2 * PPL / 4; ++i) d2[i] = p2[i];
#pragma unroll
        for (int i = 0; i < 2 * PPL / 4; ++i) dw[i] = pw[i];
    } else {
        // strided, guarded; zero weights neutralize out-of-range points
#pragma unroll
        for (int i = 0; i < PPL; ++i) {
            const int p = lane + i * 64;
            if (p < N) {
                f3[3 * i] = x3b[3 * p]; f3[3 * i + 1] = x3b[3 * p + 1]; f3[3 * i + 2] = x3b[3 * p + 2];
                f2[2 * i] = x2b[2 * p]; f2[2 * i + 1] = x2b[2 * p + 1];
                fw[2 * i] = w2b[2 * p]; fw[2 * i + 1] = w2b[2 * p + 1];
            } else {
                f3[3 * i] = f3[3 * i + 1] = f3[3 * i + 2] = 0.f;
                f2[2 * i] = f2[2 * i + 1] = 0.f;
                fw[2 * i] = fw[2 * i + 1] = 0.f;
            }
        }
    }

    // ---- per-lane (wave-uniform) control state, all f32 like the reference ----
    float JtJ[10], grad[4];
    float poseA[4], cand[4];
    float cost = 0.f, radius = 30.0f, dec = 2.0f, mcc = 0.f;
#pragma unroll
    for (int k = 0; k < 10; ++k) JtJ[k] = 0.f;
#pragma unroll
    for (int k = 0; k < 4; ++k) grad[k] = 0.f;
#pragma unroll
    for (int r = 0; r < 4; ++r) poseA[r] = pose_init[(size_t)item * 4 + r];

    float tx = poseA[0], ty = poseA[1], tz = poseA[2];
    float sn = sinf(poseA[3]), cs = cosf(poseA[3]);

    for (int it = 0; it <= NUM_ITER; ++it) {
        // K reloaded per iteration (uniform address -> L1 hit), keeps regs low
        const float* Kb = K + (size_t)item * 9;
        const float K00 = Kb[0], K01 = Kb[1], K02 = Kb[2];
        const float K10 = Kb[3], K11 = Kb[4], K12 = Kb[5];
        const float K20 = Kb[6], K21 = Kb[7], K22 = Kb[8];

        // acc: 0..9 JtJ upper-tri, 10..13 grad, 14 = sum r^2
        float acc[15];
#pragma unroll
        for (int k = 0; k < 15; ++k) acc[k] = 0.f;

#pragma unroll
        for (int i = 0; i < PPL; ++i) {
            const float X = f3[3 * i], Y = f3[3 * i + 1], Z = f3[3 * i + 2];
            const float px = fmaf(cs, X, fmaf(sn, Z, tx));
            const float py = Y + ty;
            const float pz = fmaf(-sn, X, fmaf(cs, Z, tz));
            const float nu = fmaf(K00, px, fmaf(K01, py, K02 * pz));
            const float nv = fmaf(K10, px, fmaf(K11, py, K12 * pz));
            const float w  = fmaf(K20, px, fmaf(K21, py, K22 * pz));
            const float zc  = fmaxf(w, Z_MIN);
            const float inv = 1.0f / zc;
            const float u = nu * inv, v = nv * inv;
            const float ru = (u - f2[2 * i])     * fw[2 * i];
            const float rv = (v - f2[2 * i + 1]) * fw[2 * i + 1];
            const float fl  = (w > Z_MIN) ? 1.f : 0.f;
            const float ufl = u * fl, vfl = v * fl;
            const float gu = fw[2 * i] * inv, gv = fw[2 * i + 1] * inv;
            const float a  = pz - tz;   // -s*X + c*Z
            const float bb = tx - px;   // -(c*X + s*Z)
            const float dnu3 = fmaf(K00, a, K02 * bb);
            const float dnv3 = fmaf(K10, a, K12 * bb);
            const float dw3  = fmaf(K20, a, K22 * bb);
            float Ju[4], Jv[4];
            Ju[0] = gu * fmaf(-ufl, K20, K00);  Jv[0] = gv * fmaf(-vfl, K20, K10);
            Ju[1] = gu * fmaf(-ufl, K21, K01);  Jv[1] = gv * fmaf(-vfl, K21, K11);
            Ju[2] = gu * fmaf(-ufl, K22, K02);  Jv[2] = gv * fmaf(-vfl, K22, K12);
            Ju[3] = gu * fmaf(-ufl, dw3, dnu3); Jv[3] = gv * fmaf(-vfl, dw3, dnv3);
            int idx = 0;
#pragma unroll
            for (int r = 0; r < 4; ++r)
#pragma unroll
                for (int c = r; c < 4; ++c) {
                    acc[idx] = fmaf(Ju[r], Ju[c], fmaf(Jv[r], Jv[c], acc[idx]));
                    ++idx;
                }
#pragma unroll
            for (int r = 0; r < 4; ++r)
                acc[10 + r] = fmaf(Ju[r], ru, fmaf(Jv[r], rv, acc[10 + r]));
            acc[14] = fmaf(ru, ru, fmaf(rv, rv, acc[14]));
        }

        // 64-lane butterfly: every lane ends with the full sums
#pragma unroll
        for (int k = 0; k < 15; ++k) {
            float v = acc[k];
#pragma unroll
            for (int m = 1; m < 64; m <<= 1) v += __shfl_xor(v, m, 64);
            acc[k] = v;
        }

        const float costN = 0.5f * acc[14];

        // ---- accept / reject (wave-uniform, branchless-ish, all f32) ----
        bool accept;
        if (it == 0) {
            accept = true;
        } else {
            const float rel = (cost - costN) / mcc;
            const bool success = (rel >= 1e-3f) && (mcc > 0.0f);
            if (success) {
                const float q = 2.0f * rel - 1.0f;
                const float denom = fmaxf(1.0f - q * q * q, 1.0f / 3.0f);
                radius = fminf(radius / denom, 1e16f);
                dec = 2.0f;
            } else {
                radius = radius / dec;
                dec = dec * 2.0f;
            }
            accept = success;
        }
        if (accept) {
#pragma unroll
            for (int k = 0; k < 10; ++k) JtJ[k] = acc[k];
#pragma unroll
            for (int k = 0; k < 4; ++k) grad[k] = acc[10 + k];
            cost = costN;
            if (it > 0) {
#pragma unroll
                for (int k = 0; k < 4; ++k) poseA[k] = cand[k];
            }
        }

        if (it < NUM_ITER) {
            // LM-damped solve from accepted state
            float A[10], rhs[4], stf[4];
#pragma unroll
            for (int k = 0; k < 10; ++k) A[k] = JtJ[k];
            const float dd0 = fminf(fmaxf(JtJ[0], 1e-6f), 1e32f);
            const float dd1 = fminf(fmaxf(JtJ[4], 1e-6f), 1e32f);
            const float dd2 = fminf(fmaxf(JtJ[7], 1e-6f), 1e32f);
            const float dd3 = fminf(fmaxf(JtJ[9], 1e-6f), 1e32f);
            const float irad = 1.0f / radius;
            A[0] += dd0 * irad; A[4] += dd1 * irad; A[7] += dd2 * irad; A[9] += dd3 * irad;
#pragma unroll
            for (int r = 0; r < 4; ++r) rhs[r] = -grad[r];
            solve4_spd(A, rhs, stf);
#pragma unroll
            for (int r = 0; r < 4; ++r) cand[r] = poseA[r] + stf[r];
            // model cost change with undamped JtJ
            const float s0 = stf[0], s1 = stf[1], s2 = stf[2], s3 = stf[3];
            const float Js0 = JtJ[0]*s0 + JtJ[1]*s1 + JtJ[2]*s2 + JtJ[3]*s3;
            const float Js1 = JtJ[1]*s0 + JtJ[4]*s1 + JtJ[5]*s2 + JtJ[6]*s3;
            const float Js2 = JtJ[2]*s0 + JtJ[5]*s1 + JtJ[7]*s2 + JtJ[8]*s3;
            const float Js3 = JtJ[3]*s0 + JtJ[6]*s1 + JtJ[8]*s2 + JtJ[9]*s3;
            mcc = -((s0*grad[0] + s1*grad[1] + s2*grad[2] + s3*grad[3]) +
                    0.5f * (s0*Js0 + s1*Js1 + s2*Js2 + s3*Js3));
            tx = cand[0]; ty = cand[1]; tz = cand[2];
            sn = sinf(cand[3]); cs = cosf(cand[3]);
        } else if (lane == 0) {
            // epilogue: pose_opt, cost, pose_opt + GN step
            float* out_pose = out;
            float* out_cost = out + (size_t)B * 4;
            float* out_plus = out + (size_t)B * 5;
#pragma unroll
            for (int r = 0; r < 4; ++r) out_pose[(size_t)item * 4 + r] = poseA[r];
            out_cost[item] = cost;
            float A[10], rhs[4], stf[4];
#pragma unroll
            for (int k = 0; k < 10; ++k) A[k] = JtJ[k];
            A[0] += 1e-5f; A[4] += 1e-5f; A[7] += 1e-5f; A[9] += 1e-5f;
#pragma unroll
            for (int r = 0; r < 4; ++r) rhs[r] = -grad[r];
            solve4_spd(A, rhs, stf);
#pragma unroll
            for (int r = 0; r < 4; ++r)
                out_plus[(size_t)item * 4 + r] = poseA[r] + stf[r];
        }
    }
}

extern "C" void kernel_launch(void* const* d_in, const int* in_sizes, int n_in,
                              void* d_out, int out_size, void* d_ws, size_t ws_size,
                              hipStream_t stream) {
    const float* x3d       = (const float*)d_in[0];
    const float* x2d       = (const float*)d_in[1];
    const float* w2d       = (const float*)d_in[2];
    const float* pose_init = (const float*)d_in[3];
    const float* cam       = (const float*)d_in[4];
    float* out = (float*)d_out;

    const int B = in_sizes[3] / 4;
    const int N = in_sizes[0] / (3 * B);
    const int grid = (B + 3) / 4;

    if (N == 512) {
        lm_kernel<8, true><<<grid, 256, 0, stream>>>(x3d, x2d, w2d, pose_init, cam, out, B, N);
    } else if (N == 256) {
        lm_kernel<4, true><<<grid, 256, 0, stream>>>(x3d, x2d, w2d, pose_init, cam, out, B, N);
    } else if (N <= 64) {
        lm_kernel<1, false><<<grid, 256, 0, stream>>>(x3d, x2d, w2d, pose_init, cam, out, B, N);
    } else if (N <= 128) {
        lm_kernel<2, false><<<grid, 256, 0, stream>>>(x3d, x2d, w2d, pose_init, cam, out, B, N);
    } else if (N <= 256) {
        lm_kernel<4, false><<<grid, 256, 0, stream>>>(x3d, x2d, w2d, pose_init, cam, out, B, N);
    } else if (N <= 512) {
        lm_kernel<8, false><<<grid, 256, 0, stream>>>(x3d, x2d, w2d, pose_init, cam, out, B, N);
    } else {
        lm_kernel<16, false><<<grid, 256, 0, stream>>>(x3d, x2d, w2d, pose_init, cam, out, B, N);
    }
}

// Round 3
// 518.439 us; speedup vs baseline: 1.0779x; 1.0779x over previous
//
#include <hip/hip_runtime.h>
#include <math.h>

#define NUM_ITER 10
#define Z_MIN 0.1f

// Branchless f32 LDL^T solve of 4x4 SPD system. t = upper-tri packed
// (00,01,02,03,11,12,13,22,23,33), solves A x = b.
__device__ inline void solve4_spd(const float t[10], const float b[4], float x[4]) {
    const float d0 = t[0];
    const float i0 = 1.0f / d0;
    const float L10 = t[1] * i0, L20 = t[2] * i0, L30 = t[3] * i0;
    const float d1 = t[4] - L10 * t[1];
    const float i1 = 1.0f / d1;
    const float L21 = (t[5] - L20 * t[1]) * i1;
    const float L31 = (t[6] - L30 * t[1]) * i1;
    const float d2 = t[7] - L20 * t[2] - L21 * L21 * d1;
    const float i2 = 1.0f / d2;
    const float L32 = (t[8] - L30 * t[2] - L31 * L21 * d1) * i2;
    const float d3 = t[9] - L30 * t[3] - L31 * L31 * d1 - L32 * L32 * d2;
    const float i3 = 1.0f / d3;
    const float y0 = b[0];
    const float y1 = b[1] - L10 * y0;
    const float y2 = b[2] - L20 * y0 - L21 * y1;
    const float y3 = b[3] - L30 * y0 - L31 * y1 - L32 * y2;
    const float z0 = y0 * i0, z1 = y1 * i1, z2 = y2 * i2, z3 = y3 * i3;
    x[3] = z3;
    x[2] = z2 - L32 * z3;
    x[1] = z1 - L21 * x[2] - L31 * x[3];
    x[0] = z0 - L10 * x[1] - L20 * x[2] - L30 * x[3];
}

// One wave (64 lanes) per batch item; 4 independent waves per 256-block.
// PPL points per lane, held in VGPRs (no address-of on locals -> SROA).
// EXACT: N == 64*PPL and 3*PPL%4==0 -> float4 loads of contiguous chunks.
// No LDS, no __syncthreads anywhere.
template <int PPL, bool EXACT>
__global__ __launch_bounds__(256, 4) void lm_kernel(
    const float* __restrict__ x3d, const float* __restrict__ x2d,
    const float* __restrict__ w2d, const float* __restrict__ pose_init,
    const float* __restrict__ K, float* __restrict__ out, int B, int N)
{
    const int wave = threadIdx.x >> 6;
    const int lane = threadIdx.x & 63;
    const int item = blockIdx.x * 4 + wave;
    if (item >= B) return;  // wave-uniform

    // ---- point data in registers (read exactly once) ----
    float f3[3 * PPL], f2[2 * PPL], fw[2 * PPL];
    if (EXACT) {
        // lane owns contiguous points [PPL*lane, PPL*lane+PPL).
        // float4 loads into temporaries; component-wise assignment keeps
        // the local arrays SROA-promotable (NO reinterpret_cast of locals!)
        const float4* p3 = reinterpret_cast<const float4*>(x3d + (size_t)item * N * 3) + lane * (3 * PPL / 4);
        const float4* p2 = reinterpret_cast<const float4*>(x2d + (size_t)item * N * 2) + lane * (2 * PPL / 4);
        const float4* pw = reinterpret_cast<const float4*>(w2d + (size_t)item * N * 2) + lane * (2 * PPL / 4);
#pragma unroll
        for (int i = 0; i < 3 * PPL / 4; ++i) {
            const float4 t = p3[i];
            f3[4 * i] = t.x; f3[4 * i + 1] = t.y; f3[4 * i + 2] = t.z; f3[4 * i + 3] = t.w;
        }
#pragma unroll
        for (int i = 0; i < 2 * PPL / 4; ++i) {
            const float4 t = p2[i];
            f2[4 * i] = t.x; f2[4 * i + 1] = t.y; f2[4 * i + 2] = t.z; f2[4 * i + 3] = t.w;
        }
#pragma unroll
        for (int i = 0; i < 2 * PPL / 4; ++i) {
            const float4 t = pw[i];
            fw[4 * i] = t.x; fw[4 * i + 1] = t.y; fw[4 * i + 2] = t.z; fw[4 * i + 3] = t.w;
        }
    } else {
        const float* x3b = x3d + (size_t)item * N * 3;
        const float* x2b = x2d + (size_t)item * N * 2;
        const float* w2b = w2d + (size_t)item * N * 2;
#pragma unroll
        for (int i = 0; i < PPL; ++i) {
            const int p = lane + i * 64;
            if (p < N) {
                f3[3 * i] = x3b[3 * p]; f3[3 * i + 1] = x3b[3 * p + 1]; f3[3 * i + 2] = x3b[3 * p + 2];
                f2[2 * i] = x2b[2 * p]; f2[2 * i + 1] = x2b[2 * p + 1];
                fw[2 * i] = w2b[2 * p]; fw[2 * i + 1] = w2b[2 * p + 1];
            } else {
                f3[3 * i] = f3[3 * i + 1] = f3[3 * i + 2] = 0.f;
                f2[2 * i] = f2[2 * i + 1] = 0.f;
                fw[2 * i] = fw[2 * i + 1] = 0.f;
            }
        }
    }

    // ---- wave-uniform control state (redundant on all 64 lanes, f32) ----
    float JtJ[10], grad[4];
    float cost = 0.f, radius = 30.0f, dec = 2.0f, mcc = 0.f;
#pragma unroll
    for (int k = 0; k < 10; ++k) JtJ[k] = 0.f;
#pragma unroll
    for (int k = 0; k < 4; ++k) grad[k] = 0.f;

    // accepted pose (a*) and currently-evaluated pose (e*)
    float ax = pose_init[(size_t)item * 4 + 0];
    float ay = pose_init[(size_t)item * 4 + 1];
    float az = pose_init[(size_t)item * 4 + 2];
    float ayaw = pose_init[(size_t)item * 4 + 3];
    float ex = ax, ey = ay, ez = az, eyaw = ayaw;
    float sn = sinf(eyaw), cs = cosf(eyaw);

    for (int it = 0; it <= NUM_ITER; ++it) {
        // K reloaded per iteration (uniform address -> cache hit); saves 9 regs
        const float* Kb = K + (size_t)item * 9;
        const float K00 = Kb[0], K01 = Kb[1], K02 = Kb[2];
        const float K10 = Kb[3], K11 = Kb[4], K12 = Kb[5];
        const float K20 = Kb[6], K21 = Kb[7], K22 = Kb[8];

        // acc: 0..9 JtJ upper-tri, 10..13 grad, 14 = sum r^2
        float acc[15];
#pragma unroll
        for (int k = 0; k < 15; ++k) acc[k] = 0.f;

#pragma unroll
        for (int i = 0; i < PPL; ++i) {
            const float X = f3[3 * i], Y = f3[3 * i + 1], Z = f3[3 * i + 2];
            const float px = fmaf(cs, X, fmaf(sn, Z, ex));
            const float py = Y + ey;
            const float pz = fmaf(-sn, X, fmaf(cs, Z, ez));
            const float nu = fmaf(K00, px, fmaf(K01, py, K02 * pz));
            const float nv = fmaf(K10, px, fmaf(K11, py, K12 * pz));
            const float w  = fmaf(K20, px, fmaf(K21, py, K22 * pz));
            const float zc  = fmaxf(w, Z_MIN);
            const float inv = 1.0f / zc;
            const float u = nu * inv, v = nv * inv;
            const float ru = (u - f2[2 * i])     * fw[2 * i];
            const float rv = (v - f2[2 * i + 1]) * fw[2 * i + 1];
            const float fl  = (w > Z_MIN) ? 1.f : 0.f;
            const float ufl = u * fl, vfl = v * fl;
            const float gu = fw[2 * i] * inv, gv = fw[2 * i + 1] * inv;
            const float a  = pz - ez;   // -s*X + c*Z
            const float bb = ex - px;   // -(c*X + s*Z)
            const float dnu3 = fmaf(K00, a, K02 * bb);
            const float dnv3 = fmaf(K10, a, K12 * bb);
            const float dw3  = fmaf(K20, a, K22 * bb);
            float Ju[4], Jv[4];
            Ju[0] = gu * fmaf(-ufl, K20, K00);  Jv[0] = gv * fmaf(-vfl, K20, K10);
            Ju[1] = gu * fmaf(-ufl, K21, K01);  Jv[1] = gv * fmaf(-vfl, K21, K11);
            Ju[2] = gu * fmaf(-ufl, K22, K02);  Jv[2] = gv * fmaf(-vfl, K22, K12);
            Ju[3] = gu * fmaf(-ufl, dw3, dnu3); Jv[3] = gv * fmaf(-vfl, dw3, dnv3);
            int idx = 0;
#pragma unroll
            for (int r = 0; r < 4; ++r)
#pragma unroll
                for (int c = r; c < 4; ++c) {
                    acc[idx] = fmaf(Ju[r], Ju[c], fmaf(Jv[r], Jv[c], acc[idx]));
                    ++idx;
                }
#pragma unroll
            for (int r = 0; r < 4; ++r)
                acc[10 + r] = fmaf(Ju[r], ru, fmaf(Jv[r], rv, acc[10 + r]));
            acc[14] = fmaf(ru, ru, fmaf(rv, rv, acc[14]));
        }

        // 64-lane butterfly: every lane ends with the full sums
#pragma unroll
        for (int k = 0; k < 15; ++k) {
            float v = acc[k];
#pragma unroll
            for (int m = 1; m < 64; m <<= 1) v += __shfl_xor(v, m, 64);
            acc[k] = v;
        }

        const float costN = 0.5f * acc[14];

        // ---- accept / reject (wave-uniform, f32 like reference) ----
        bool accept;
        if (it == 0) {
            accept = true;
        } else {
            const float rel = (cost - costN) / mcc;
            const bool success = (rel >= 1e-3f) && (mcc > 0.0f);
            if (success) {
                const float q = 2.0f * rel - 1.0f;
                const float denom = fmaxf(1.0f - q * q * q, 1.0f / 3.0f);
                radius = fminf(radius / denom, 1e16f);
                dec = 2.0f;
            } else {
                radius = radius / dec;
                dec = dec * 2.0f;
            }
            accept = success;
        }
        if (accept) {
#pragma unroll
            for (int k = 0; k < 10; ++k) JtJ[k] = acc[k];
#pragma unroll
            for (int k = 0; k < 4; ++k) grad[k] = acc[10 + k];
            cost = costN;
            if (it > 0) { ax = ex; ay = ey; az = ez; ayaw = eyaw; }
        }

        if (it < NUM_ITER) {
            // LM-damped solve from accepted state
            float A[10], rhs[4], stf[4];
#pragma unroll
            for (int k = 0; k < 10; ++k) A[k] = JtJ[k];
            const float irad = 1.0f / radius;
            A[0] += fminf(fmaxf(JtJ[0], 1e-6f), 1e32f) * irad;
            A[4] += fminf(fmaxf(JtJ[4], 1e-6f), 1e32f) * irad;
            A[7] += fminf(fmaxf(JtJ[7], 1e-6f), 1e32f) * irad;
            A[9] += fminf(fmaxf(JtJ[9], 1e-6f), 1e32f) * irad;
#pragma unroll
            for (int r = 0; r < 4; ++r) rhs[r] = -grad[r];
            solve4_spd(A, rhs, stf);
            ex = ax + stf[0]; ey = ay + stf[1]; ez = az + stf[2]; eyaw = ayaw + stf[3];
            // model cost change with undamped JtJ
            const float s0 = stf[0], s1 = stf[1], s2 = stf[2], s3 = stf[3];
            const float Js0 = JtJ[0]*s0 + JtJ[1]*s1 + JtJ[2]*s2 + JtJ[3]*s3;
            const float Js1 = JtJ[1]*s0 + JtJ[4]*s1 + JtJ[5]*s2 + JtJ[6]*s3;
            const float Js2 = JtJ[2]*s0 + JtJ[5]*s1 + JtJ[7]*s2 + JtJ[8]*s3;
            const float Js3 = JtJ[3]*s0 + JtJ[6]*s1 + JtJ[8]*s2 + JtJ[9]*s3;
            mcc = -((s0*grad[0] + s1*grad[1] + s2*grad[2] + s3*grad[3]) +
                    0.5f * (s0*Js0 + s1*Js1 + s2*Js2 + s3*Js3));
            sn = sinf(eyaw); cs = cosf(eyaw);
        } else if (lane == 0) {
            // epilogue: pose_opt, cost, pose_opt + GN step
            float* out_pose = out;
            float* out_cost = out + (size_t)B * 4;
            float* out_plus = out + (size_t)B * 5;
            out_pose[(size_t)item * 4 + 0] = ax;
            out_pose[(size_t)item * 4 + 1] = ay;
            out_pose[(size_t)item * 4 + 2] = az;
            out_pose[(size_t)item * 4 + 3] = ayaw;
            out_cost[item] = cost;
            float A[10], rhs[4], stf[4];
#pragma unroll
            for (int k = 0; k < 10; ++k) A[k] = JtJ[k];
            A[0] += 1e-5f; A[4] += 1e-5f; A[7] += 1e-5f; A[9] += 1e-5f;
#pragma unroll
            for (int r = 0; r < 4; ++r) rhs[r] = -grad[r];
            solve4_spd(A, rhs, stf);
            out_plus[(size_t)item * 4 + 0] = ax + stf[0];
            out_plus[(size_t)item * 4 + 1] = ay + stf[1];
            out_plus[(size_t)item * 4 + 2] = az + stf[2];
            out_plus[(size_t)item * 4 + 3] = ayaw + stf[3];
        }
    }
}

extern "C" void kernel_launch(void* const* d_in, const int* in_sizes, int n_in,
                              void* d_out, int out_size, void* d_ws, size_t ws_size,
                              hipStream_t stream) {
    const float* x3d       = (const float*)d_in[0];
    const float* x2d       = (const float*)d_in[1];
    const float* w2d       = (const float*)d_in[2];
    const float* pose_init = (const float*)d_in[3];
    const float* cam       = (const float*)d_in[4];
    float* out = (float*)d_out;

    const int B = in_sizes[3] / 4;
    const int N = in_sizes[0] / (3 * B);
    const int grid = (B + 3) / 4;

    if (N == 512) {
        lm_kernel<8, true><<<grid, 256, 0, stream>>>(x3d, x2d, w2d, pose_init, cam, out, B, N);
    } else if (N == 256) {
        lm_kernel<4, true><<<grid, 256, 0, stream>>>(x3d, x2d, w2d, pose_init, cam, out, B, N);
    } else if (N <= 64) {
        lm_kernel<1, false><<<grid, 256, 0, stream>>>(x3d, x2d, w2d, pose_init, cam, out, B, N);
    } else if (N <= 128) {
        lm_kernel<2, false><<<grid, 256, 0, stream>>>(x3d, x2d, w2d, pose_init, cam, out, B, N);
    } else if (N <= 256) {
        lm_kernel<4, false><<<grid, 256, 0, stream>>>(x3d, x2d, w2d, pose_init, cam, out, B, N);
    } else if (N <= 512) {
        lm_kernel<8, false><<<grid, 256, 0, stream>>>(x3d, x2d, w2d, pose_init, cam, out, B, N);
    } else {
        lm_kernel<16, false><<<grid, 256, 0, stream>>>(x3d, x2d, w2d, pose_init, cam, out, B, N);
    }
}

// Round 4
// 169.774 us; speedup vs baseline: 3.2917x; 3.0537x over previous
//
#include <hip/hip_runtime.h>
#include <math.h>

#define NUM_ITER 10
#define Z_MIN 0.1f

__device__ inline float uniform_f(float v) {
    // item is wave-uniform -> force value into an SGPR
    return __int_as_float(__builtin_amdgcn_readfirstlane(__float_as_int(v)));
}

// Branchless f32 LDL^T solve of 4x4 SPD system. t = upper-tri packed
// (00,01,02,03,11,12,13,22,23,33), solves A x = b.
__device__ inline void solve4_spd(const float t[10], const float b[4], float x[4]) {
    const float d0 = t[0];
    const float i0 = 1.0f / d0;
    const float L10 = t[1] * i0, L20 = t[2] * i0, L30 = t[3] * i0;
    const float d1 = t[4] - L10 * t[1];
    const float i1 = 1.0f / d1;
    const float L21 = (t[5] - L20 * t[1]) * i1;
    const float L31 = (t[6] - L30 * t[1]) * i1;
    const float d2 = t[7] - L20 * t[2] - L21 * L21 * d1;
    const float i2 = 1.0f / d2;
    const float L32 = (t[8] - L30 * t[2] - L31 * L21 * d1) * i2;
    const float d3 = t[9] - L30 * t[3] - L31 * L31 * d1 - L32 * L32 * d2;
    const float i3 = 1.0f / d3;
    const float y0 = b[0];
    const float y1 = b[1] - L10 * y0;
    const float y2 = b[2] - L20 * y0 - L21 * y1;
    const float y3 = b[3] - L30 * y0 - L31 * y1 - L32 * y2;
    const float z0 = y0 * i0, z1 = y1 * i1, z2 = y2 * i2, z3 = y3 * i3;
    x[3] = z3;
    x[2] = z2 - L32 * z3;
    x[1] = z1 - L21 * x[2] - L31 * x[3];
    x[0] = z0 - L10 * x[1] - L20 * x[2] - L30 * x[3];
}

// One wave (64 lanes) per batch item; 4 independent waves per 256-block.
// PPL points per lane held in VGPRs. NO launch-bounds occupancy demand:
// a min-waves cap forces the allocator past its budget and it spills the
// point arrays to scratch wholesale (rounds 2-3: 0.9 GB scratch traffic).
// EXACT: N == 64*PPL -> float4 loads of contiguous per-lane chunks.
// No LDS, no __syncthreads anywhere.
template <int PPL, bool EXACT>
__global__ __launch_bounds__(256) void lm_kernel(
    const float* __restrict__ x3d, const float* __restrict__ x2d,
    const float* __restrict__ w2d, const float* __restrict__ pose_init,
    const float* __restrict__ K, float* __restrict__ out, int B, int N)
{
    const int wave = threadIdx.x >> 6;
    const int lane = threadIdx.x & 63;
    const int item = blockIdx.x * 4 + wave;
    if (item >= B) return;  // wave-uniform

    // ---- point data in registers (read exactly once) ----
    float f3[3 * PPL], f2[2 * PPL], fw[2 * PPL];
    if (EXACT) {
        const float4* p3 = reinterpret_cast<const float4*>(x3d + (size_t)item * N * 3) + lane * (3 * PPL / 4);
        const float4* p2 = reinterpret_cast<const float4*>(x2d + (size_t)item * N * 2) + lane * (2 * PPL / 4);
        const float4* pw = reinterpret_cast<const float4*>(w2d + (size_t)item * N * 2) + lane * (2 * PPL / 4);
#pragma unroll
        for (int i = 0; i < 3 * PPL / 4; ++i) {
            const float4 t = p3[i];
            f3[4 * i] = t.x; f3[4 * i + 1] = t.y; f3[4 * i + 2] = t.z; f3[4 * i + 3] = t.w;
        }
#pragma unroll
        for (int i = 0; i < 2 * PPL / 4; ++i) {
            const float4 t = p2[i];
            f2[4 * i] = t.x; f2[4 * i + 1] = t.y; f2[4 * i + 2] = t.z; f2[4 * i + 3] = t.w;
        }
#pragma unroll
        for (int i = 0; i < 2 * PPL / 4; ++i) {
            const float4 t = pw[i];
            fw[4 * i] = t.x; fw[4 * i + 1] = t.y; fw[4 * i + 2] = t.z; fw[4 * i + 3] = t.w;
        }
    } else {
        const float* x3b = x3d + (size_t)item * N * 3;
        const float* x2b = x2d + (size_t)item * N * 2;
        const float* w2b = w2d + (size_t)item * N * 2;
#pragma unroll
        for (int i = 0; i < PPL; ++i) {
            const int p = lane + i * 64;
            if (p < N) {
                f3[3 * i] = x3b[3 * p]; f3[3 * i + 1] = x3b[3 * p + 1]; f3[3 * i + 2] = x3b[3 * p + 2];
                f2[2 * i] = x2b[2 * p]; f2[2 * i + 1] = x2b[2 * p + 1];
                fw[2 * i] = w2b[2 * p]; fw[2 * i + 1] = w2b[2 * p + 1];
            } else {
                f3[3 * i] = f3[3 * i + 1] = f3[3 * i + 2] = 0.f;
                f2[2 * i] = f2[2 * i + 1] = 0.f;
                fw[2 * i] = fw[2 * i + 1] = 0.f;
            }
        }
    }

    // ---- K: loop-invariant, wave-uniform -> SGPRs via readfirstlane ----
    const float* Kb = K + (size_t)item * 9;
    const float K00 = uniform_f(Kb[0]), K01 = uniform_f(Kb[1]), K02 = uniform_f(Kb[2]);
    const float K10 = uniform_f(Kb[3]), K11 = uniform_f(Kb[4]), K12 = uniform_f(Kb[5]);
    const float K20 = uniform_f(Kb[6]), K21 = uniform_f(Kb[7]), K22 = uniform_f(Kb[8]);

    // ---- wave-uniform control state (redundant on all 64 lanes, f32) ----
    float JtJ[10], grad[4];
    float cost = 0.f, radius = 30.0f, dec = 2.0f, mcc = 0.f;
#pragma unroll
    for (int k = 0; k < 10; ++k) JtJ[k] = 0.f;
#pragma unroll
    for (int k = 0; k < 4; ++k) grad[k] = 0.f;

    // accepted pose (a*) and currently-evaluated pose (e*)
    float ax = pose_init[(size_t)item * 4 + 0];
    float ay = pose_init[(size_t)item * 4 + 1];
    float az = pose_init[(size_t)item * 4 + 2];
    float ayaw = pose_init[(size_t)item * 4 + 3];
    float ex = ax, ey = ay, ez = az, eyaw = ayaw;
    float sn = sinf(eyaw), cs = cosf(eyaw);

    for (int it = 0; it <= NUM_ITER; ++it) {
        // acc: 0..9 JtJ upper-tri, 10..13 grad, 14 = sum r^2
        float acc[15];
#pragma unroll
        for (int k = 0; k < 15; ++k) acc[k] = 0.f;

#pragma unroll
        for (int i = 0; i < PPL; ++i) {
            const float X = f3[3 * i], Y = f3[3 * i + 1], Z = f3[3 * i + 2];
            const float px = fmaf(cs, X, fmaf(sn, Z, ex));
            const float py = Y + ey;
            const float pz = fmaf(-sn, X, fmaf(cs, Z, ez));
            const float nu = fmaf(K00, px, fmaf(K01, py, K02 * pz));
            const float nv = fmaf(K10, px, fmaf(K11, py, K12 * pz));
            const float w  = fmaf(K20, px, fmaf(K21, py, K22 * pz));
            const float zc  = fmaxf(w, Z_MIN);
            const float inv = 1.0f / zc;
            const float u = nu * inv, v = nv * inv;
            const float ru = (u - f2[2 * i])     * fw[2 * i];
            const float rv = (v - f2[2 * i + 1]) * fw[2 * i + 1];
            const float fl  = (w > Z_MIN) ? 1.f : 0.f;
            const float ufl = u * fl, vfl = v * fl;
            const float gu = fw[2 * i] * inv, gv = fw[2 * i + 1] * inv;
            const float a  = pz - ez;   // -s*X + c*Z
            const float bb = ex - px;   // -(c*X + s*Z)
            const float dnu3 = fmaf(K00, a, K02 * bb);
            const float dnv3 = fmaf(K10, a, K12 * bb);
            const float dw3  = fmaf(K20, a, K22 * bb);
            float Ju[4], Jv[4];
            Ju[0] = gu * fmaf(-ufl, K20, K00);  Jv[0] = gv * fmaf(-vfl, K20, K10);
            Ju[1] = gu * fmaf(-ufl, K21, K01);  Jv[1] = gv * fmaf(-vfl, K21, K11);
            Ju[2] = gu * fmaf(-ufl, K22, K02);  Jv[2] = gv * fmaf(-vfl, K22, K12);
            Ju[3] = gu * fmaf(-ufl, dw3, dnu3); Jv[3] = gv * fmaf(-vfl, dw3, dnv3);
            int idx = 0;
#pragma unroll
            for (int r = 0; r < 4; ++r)
#pragma unroll
                for (int c = r; c < 4; ++c) {
                    acc[idx] = fmaf(Ju[r], Ju[c], fmaf(Jv[r], Jv[c], acc[idx]));
                    ++idx;
                }
#pragma unroll
            for (int r = 0; r < 4; ++r)
                acc[10 + r] = fmaf(Ju[r], ru, fmaf(Jv[r], rv, acc[10 + r]));
            acc[14] = fmaf(ru, ru, fmaf(rv, rv, acc[14]));
        }

        // 64-lane butterfly: every lane ends with the full sums
#pragma unroll
        for (int k = 0; k < 15; ++k) {
            float v = acc[k];
#pragma unroll
            for (int m = 1; m < 64; m <<= 1) v += __shfl_xor(v, m, 64);
            acc[k] = v;
        }

        const float costN = 0.5f * acc[14];

        // ---- accept / reject (wave-uniform, f32 like reference) ----
        bool accept;
        if (it == 0) {
            accept = true;
        } else {
            const float rel = (cost - costN) / mcc;
            const bool success = (rel >= 1e-3f) && (mcc > 0.0f);
            if (success) {
                const float q = 2.0f * rel - 1.0f;
                const float denom = fmaxf(1.0f - q * q * q, 1.0f / 3.0f);
                radius = fminf(radius / denom, 1e16f);
                dec = 2.0f;
            } else {
                radius = radius / dec;
                dec = dec * 2.0f;
            }
            accept = success;
        }
        if (accept) {
#pragma unroll
            for (int k = 0; k < 10; ++k) JtJ[k] = acc[k];
#pragma unroll
            for (int k = 0; k < 4; ++k) grad[k] = acc[10 + k];
            cost = costN;
            if (it > 0) { ax = ex; ay = ey; az = ez; ayaw = eyaw; }
        }

        if (it < NUM_ITER) {
            // LM-damped solve from accepted state
            float A[10], rhs[4], stf[4];
#pragma unroll
            for (int k = 0; k < 10; ++k) A[k] = JtJ[k];
            const float irad = 1.0f / radius;
            A[0] += fminf(fmaxf(JtJ[0], 1e-6f), 1e32f) * irad;
            A[4] += fminf(fmaxf(JtJ[4], 1e-6f), 1e32f) * irad;
            A[7] += fminf(fmaxf(JtJ[7], 1e-6f), 1e32f) * irad;
            A[9] += fminf(fmaxf(JtJ[9], 1e-6f), 1e32f) * irad;
#pragma unroll
            for (int r = 0; r < 4; ++r) rhs[r] = -grad[r];
            solve4_spd(A, rhs, stf);
            ex = ax + stf[0]; ey = ay + stf[1]; ez = az + stf[2]; eyaw = ayaw + stf[3];
            // model cost change with undamped JtJ
            const float s0 = stf[0], s1 = stf[1], s2 = stf[2], s3 = stf[3];
            const float Js0 = JtJ[0]*s0 + JtJ[1]*s1 + JtJ[2]*s2 + JtJ[3]*s3;
            const float Js1 = JtJ[1]*s0 + JtJ[4]*s1 + JtJ[5]*s2 + JtJ[6]*s3;
            const float Js2 = JtJ[2]*s0 + JtJ[5]*s1 + JtJ[7]*s2 + JtJ[8]*s3;
            const float Js3 = JtJ[3]*s0 + JtJ[6]*s1 + JtJ[8]*s2 + JtJ[9]*s3;
            mcc = -((s0*grad[0] + s1*grad[1] + s2*grad[2] + s3*grad[3]) +
                    0.5f * (s0*Js0 + s1*Js1 + s2*Js2 + s3*Js3));
            sn = sinf(eyaw); cs = cosf(eyaw);
        } else if (lane == 0) {
            // epilogue: pose_opt, cost, pose_opt + GN step
            float* out_pose = out;
            float* out_cost = out + (size_t)B * 4;
            float* out_plus = out + (size_t)B * 5;
            out_pose[(size_t)item * 4 + 0] = ax;
            out_pose[(size_t)item * 4 + 1] = ay;
            out_pose[(size_t)item * 4 + 2] = az;
            out_pose[(size_t)item * 4 + 3] = ayaw;
            out_cost[item] = cost;
            float A[10], rhs[4], stf[4];
#pragma unroll
            for (int k = 0; k < 10; ++k) A[k] = JtJ[k];
            A[0] += 1e-5f; A[4] += 1e-5f; A[7] += 1e-5f; A[9] += 1e-5f;
#pragma unroll
            for (int r = 0; r < 4; ++r) rhs[r] = -grad[r];
            solve4_spd(A, rhs, stf);
            out_plus[(size_t)item * 4 + 0] = ax + stf[0];
            out_plus[(size_t)item * 4 + 1] = ay + stf[1];
            out_plus[(size_t)item * 4 + 2] = az + stf[2];
            out_plus[(size_t)item * 4 + 3] = ayaw + stf[3];
        }
    }
}

extern "C" void kernel_launch(void* const* d_in, const int* in_sizes, int n_in,
                              void* d_out, int out_size, void* d_ws, size_t ws_size,
                              hipStream_t stream) {
    const float* x3d       = (const float*)d_in[0];
    const float* x2d       = (const float*)d_in[1];
    const float* w2d       = (const float*)d_in[2];
    const float* pose_init = (const float*)d_in[3];
    const float* cam       = (const float*)d_in[4];
    float* out = (float*)d_out;

    const int B = in_sizes[3] / 4;
    const int N = in_sizes[0] / (3 * B);
    const int grid = (B + 3) / 4;

    if (N == 512) {
        lm_kernel<8, true><<<grid, 256, 0, stream>>>(x3d, x2d, w2d, pose_init, cam, out, B, N);
    } else if (N == 256) {
        lm_kernel<4, true><<<grid, 256, 0, stream>>>(x3d, x2d, w2d, pose_init, cam, out, B, N);
    } else if (N <= 64) {
        lm_kernel<1, false><<<grid, 256, 0, stream>>>(x3d, x2d, w2d, pose_init, cam, out, B, N);
    } else if (N <= 128) {
        lm_kernel<2, false><<<grid, 256, 0, stream>>>(x3d, x2d, w2d, pose_init, cam, out, B, N);
    } else if (N <= 256) {
        lm_kernel<4, false><<<grid, 256, 0, stream>>>(x3d, x2d, w2d, pose_init, cam, out, B, N);
    } else if (N <= 512) {
        lm_kernel<8, false><<<grid, 256, 0, stream>>>(x3d, x2d, w2d, pose_init, cam, out, B, N);
    } else {
        lm_kernel<16, false><<<grid, 256, 0, stream>>>(x3d, x2d, w2d, pose_init, cam, out, B, N);
    }
}

// Round 5
// 152.615 us; speedup vs baseline: 3.6618x; 1.1124x over previous
//
#include <hip/hip_runtime.h>
#include <math.h>

#define NUM_ITER 10
#define Z_MIN 0.1f

__device__ inline float uniform_f(float v) {
    // item is wave-uniform -> force value into an SGPR
    return __int_as_float(__builtin_amdgcn_readfirstlane(__float_as_int(v)));
}

// Full-wave (64-lane) all-reduce sum.
// Rows of 16: rotate-allreduce via DPP row_ror (VALU-rate, no LDS pipe),
// then cross-row via 2 shuffles. Every lane ends with the total.
__device__ inline float wave_allreduce(float x) {
    int t;
    t = __builtin_amdgcn_update_dpp(0, __float_as_int(x), 0x121, 0xf, 0xf, true); x += __int_as_float(t); // ror:1
    t = __builtin_amdgcn_update_dpp(0, __float_as_int(x), 0x122, 0xf, 0xf, true); x += __int_as_float(t); // ror:2
    t = __builtin_amdgcn_update_dpp(0, __float_as_int(x), 0x124, 0xf, 0xf, true); x += __int_as_float(t); // ror:4
    t = __builtin_amdgcn_update_dpp(0, __float_as_int(x), 0x128, 0xf, 0xf, true); x += __int_as_float(t); // ror:8
    x += __shfl_xor(x, 16, 64);
    x += __shfl_xor(x, 32, 64);
    return x;
}

// Branchless f32 LDL^T solve of 4x4 SPD system. t = upper-tri packed
// (00,01,02,03,11,12,13,22,23,33), solves A x = b.
__device__ inline void solve4_spd(const float t[10], const float b[4], float x[4]) {
    const float d0 = t[0];
    const float i0 = 1.0f / d0;
    const float L10 = t[1] * i0, L20 = t[2] * i0, L30 = t[3] * i0;
    const float d1 = t[4] - L10 * t[1];
    const float i1 = 1.0f / d1;
    const float L21 = (t[5] - L20 * t[1]) * i1;
    const float L31 = (t[6] - L30 * t[1]) * i1;
    const float d2 = t[7] - L20 * t[2] - L21 * L21 * d1;
    const float i2 = 1.0f / d2;
    const float L32 = (t[8] - L30 * t[2] - L31 * L21 * d1) * i2;
    const float d3 = t[9] - L30 * t[3] - L31 * L31 * d1 - L32 * L32 * d2;
    const float i3 = 1.0f / d3;
    const float y0 = b[0];
    const float y1 = b[1] - L10 * y0;
    const float y2 = b[2] - L20 * y0 - L21 * y1;
    const float y3 = b[3] - L30 * y0 - L31 * y1 - L32 * y2;
    const float z0 = y0 * i0, z1 = y1 * i1, z2 = y2 * i2, z3 = y3 * i3;
    x[3] = z3;
    x[2] = z2 - L32 * z3;
    x[1] = z1 - L21 * x[2] - L31 * x[3];
    x[0] = z0 - L10 * x[1] - L20 * x[2] - L30 * x[3];
}

// One wave (64 lanes) per batch item; 4 independent waves per 256-block.
// PPL points per lane held in VGPRs. NO min-waves launch-bounds arg: a
// register cap makes the allocator dump the point arrays to scratch
// (rounds 2-3: 0.9 GB scratch traffic). No LDS, no __syncthreads.
// EXACT: N == 64*PPL -> float4 loads of contiguous per-lane chunks.
template <int PPL, bool EXACT>
__global__ __launch_bounds__(256) void lm_kernel(
    const float* __restrict__ x3d, const float* __restrict__ x2d,
    const float* __restrict__ w2d, const float* __restrict__ pose_init,
    const float* __restrict__ K, float* __restrict__ out, int B, int N)
{
    const int wave = threadIdx.x >> 6;
    const int lane = threadIdx.x & 63;
    const int item = blockIdx.x * 4 + wave;
    if (item >= B) return;  // wave-uniform

    // ---- point data in registers (read exactly once) ----
    // f3: X,Y,Z   fw: wu,wv   fp: wu*u_obs, wv*v_obs (pre-multiplied targets)
    float f3[3 * PPL], fp[2 * PPL], fw[2 * PPL];
    if (EXACT) {
        const float4* p3 = reinterpret_cast<const float4*>(x3d + (size_t)item * N * 3) + lane * (3 * PPL / 4);
        const float4* p2 = reinterpret_cast<const float4*>(x2d + (size_t)item * N * 2) + lane * (2 * PPL / 4);
        const float4* pw = reinterpret_cast<const float4*>(w2d + (size_t)item * N * 2) + lane * (2 * PPL / 4);
#pragma unroll
        for (int i = 0; i < 3 * PPL / 4; ++i) {
            const float4 t = p3[i];
            f3[4 * i] = t.x; f3[4 * i + 1] = t.y; f3[4 * i + 2] = t.z; f3[4 * i + 3] = t.w;
        }
#pragma unroll
        for (int i = 0; i < 2 * PPL / 4; ++i) {
            const float4 t = pw[i];
            fw[4 * i] = t.x; fw[4 * i + 1] = t.y; fw[4 * i + 2] = t.z; fw[4 * i + 3] = t.w;
        }
#pragma unroll
        for (int i = 0; i < 2 * PPL / 4; ++i) {
            const float4 t = p2[i];
            fp[4 * i]     = t.x * fw[4 * i];
            fp[4 * i + 1] = t.y * fw[4 * i + 1];
            fp[4 * i + 2] = t.z * fw[4 * i + 2];
            fp[4 * i + 3] = t.w * fw[4 * i + 3];
        }
    } else {
        const float* x3b = x3d + (size_t)item * N * 3;
        const float* x2b = x2d + (size_t)item * N * 2;
        const float* w2b = w2d + (size_t)item * N * 2;
#pragma unroll
        for (int i = 0; i < PPL; ++i) {
            const int p = lane + i * 64;
            if (p < N) {
                f3[3 * i] = x3b[3 * p]; f3[3 * i + 1] = x3b[3 * p + 1]; f3[3 * i + 2] = x3b[3 * p + 2];
                fw[2 * i] = w2b[2 * p]; fw[2 * i + 1] = w2b[2 * p + 1];
                fp[2 * i] = x2b[2 * p] * fw[2 * i]; fp[2 * i + 1] = x2b[2 * p + 1] * fw[2 * i + 1];
            } else {
                f3[3 * i] = f3[3 * i + 1] = f3[3 * i + 2] = 0.f;
                fw[2 * i] = fw[2 * i + 1] = 0.f;
                fp[2 * i] = fp[2 * i + 1] = 0.f;
            }
        }
    }

    // ---- K: loop-invariant, wave-uniform -> SGPRs ----
    const float* Kb = K + (size_t)item * 9;
    const float K00 = uniform_f(Kb[0]), K01 = uniform_f(Kb[1]), K02 = uniform_f(Kb[2]);
    const float K10 = uniform_f(Kb[3]), K11 = uniform_f(Kb[4]), K12 = uniform_f(Kb[5]);
    const float K20 = uniform_f(Kb[6]), K21 = uniform_f(Kb[7]), K22 = uniform_f(Kb[8]);
    // pinhole form [[fx,0,cx],[0,fy,cy],[0,0,1]] -> big algebraic shortcuts
    const bool spec = (K01 == 0.f) && (K10 == 0.f) && (K20 == 0.f) &&
                      (K21 == 0.f) && (K22 == 1.f);

    // ---- wave-uniform control state (redundant on all 64 lanes, f32) ----
    float JtJ[10], grad[4];
    float cost = 0.f, radius = 30.0f, dec = 2.0f, mcc = 0.f;
#pragma unroll
    for (int k = 0; k < 10; ++k) JtJ[k] = 0.f;
#pragma unroll
    for (int k = 0; k < 4; ++k) grad[k] = 0.f;

    // accepted pose (a*) and currently-evaluated pose (e*)
    float ax = pose_init[(size_t)item * 4 + 0];
    float ay = pose_init[(size_t)item * 4 + 1];
    float az = pose_init[(size_t)item * 4 + 2];
    float ayaw = pose_init[(size_t)item * 4 + 3];
    float ex = ax, ey = ay, ez = az, eyaw = ayaw;
    float sn = __sinf(eyaw), cs = __cosf(eyaw);

    for (int it = 0; it <= NUM_ITER; ++it) {
        // acc: 0..9 JtJ upper-tri (00,01,02,03,11,12,13,22,23,33),
        //      10..13 grad, 14 = sum r^2.  acc[1] stays 0 in spec path.
        float acc[15];
#pragma unroll
        for (int k = 0; k < 15; ++k) acc[k] = 0.f;

        if (spec) {
#pragma unroll
            for (int i = 0; i < PPL; ++i) {
                const float X = f3[3 * i], Y = f3[3 * i + 1], Z = f3[3 * i + 2];
                const float px = fmaf(cs, X, fmaf(sn, Z, ex));
                const float py = Y + ey;
                const float pz = fmaf(-sn, X, fmaf(cs, Z, ez));
                const float nu = fmaf(K00, px, K02 * pz);
                const float nv = fmaf(K11, py, K12 * pz);
                const float zc = fmaxf(pz, Z_MIN);
                const float inv = 1.0f / zc;
                const float gu = fw[2 * i] * inv, gv = fw[2 * i + 1] * inv;
                const float ru = fmaf(nu, gu, -fp[2 * i]);
                const float rv = fmaf(nv, gv, -fp[2 * i + 1]);
                const float u = nu * inv, v = nv * inv;
                const bool in = (pz > Z_MIN);
                const float ufl = in ? u : 0.f;
                const float vfl = in ? v : 0.f;
                const float a  = pz - ez;   // -s*X + c*Z
                const float bb = ex - px;   // -(c*X + s*Z)
                const float Ju0 = gu * K00;
                const float Jv1 = gv * K11;
                const float Ju2 = gu * (K02 - ufl);
                const float Jv2 = gv * (K12 - vfl);
                const float Ju3 = fmaf(Ju0, a, Ju2 * bb);
                const float Jv3 = Jv2 * bb;
                acc[0]  = fmaf(Ju0, Ju0, acc[0]);
                acc[2]  = fmaf(Ju0, Ju2, acc[2]);
                acc[3]  = fmaf(Ju0, Ju3, acc[3]);
                acc[4]  = fmaf(Jv1, Jv1, acc[4]);
                acc[5]  = fmaf(Jv1, Jv2, acc[5]);
                acc[6]  = fmaf(Jv1, Jv3, acc[6]);
                acc[7]  = fmaf(Ju2, Ju2, fmaf(Jv2, Jv2, acc[7]));
                acc[8]  = fmaf(Ju2, Ju3, fmaf(Jv2, Jv3, acc[8]));
                acc[9]  = fmaf(Ju3, Ju3, fmaf(Jv3, Jv3, acc[9]));
                acc[10] = fmaf(Ju0, ru, acc[10]);
                acc[11] = fmaf(Jv1, rv, acc[11]);
                acc[12] = fmaf(Ju2, ru, fmaf(Jv2, rv, acc[12]));
                acc[13] = fmaf(Ju3, ru, fmaf(Jv3, rv, acc[13]));
                acc[14] = fmaf(ru, ru, fmaf(rv, rv, acc[14]));
            }
        } else {
#pragma unroll
            for (int i = 0; i < PPL; ++i) {
                const float X = f3[3 * i], Y = f3[3 * i + 1], Z = f3[3 * i + 2];
                const float px = fmaf(cs, X, fmaf(sn, Z, ex));
                const float py = Y + ey;
                const float pz = fmaf(-sn, X, fmaf(cs, Z, ez));
                const float nu = fmaf(K00, px, fmaf(K01, py, K02 * pz));
                const float nv = fmaf(K10, px, fmaf(K11, py, K12 * pz));
                const float w  = fmaf(K20, px, fmaf(K21, py, K22 * pz));
                const float zc  = fmaxf(w, Z_MIN);
                const float inv = 1.0f / zc;
                const float gu = fw[2 * i] * inv, gv = fw[2 * i + 1] * inv;
                const float ru = fmaf(nu, gu, -fp[2 * i]);
                const float rv = fmaf(nv, gv, -fp[2 * i + 1]);
                const float u = nu * inv, v = nv * inv;
                const float fl  = (w > Z_MIN) ? 1.f : 0.f;
                const float ufl = u * fl, vfl = v * fl;
                const float a  = pz - ez;
                const float bb = ex - px;
                const float dnu3 = fmaf(K00, a, K02 * bb);
                const float dnv3 = fmaf(K10, a, K12 * bb);
                const float dw3  = fmaf(K20, a, K22 * bb);
                float Ju[4], Jv[4];
                Ju[0] = gu * fmaf(-ufl, K20, K00);  Jv[0] = gv * fmaf(-vfl, K20, K10);
                Ju[1] = gu * fmaf(-ufl, K21, K01);  Jv[1] = gv * fmaf(-vfl, K21, K11);
                Ju[2] = gu * fmaf(-ufl, K22, K02);  Jv[2] = gv * fmaf(-vfl, K22, K12);
                Ju[3] = gu * fmaf(-ufl, dw3, dnu3); Jv[3] = gv * fmaf(-vfl, dw3, dnv3);
                int idx = 0;
#pragma unroll
                for (int r = 0; r < 4; ++r)
#pragma unroll
                    for (int c = r; c < 4; ++c) {
                        acc[idx] = fmaf(Ju[r], Ju[c], fmaf(Jv[r], Jv[c], acc[idx]));
                        ++idx;
                    }
#pragma unroll
                for (int r = 0; r < 4; ++r)
                    acc[10 + r] = fmaf(Ju[r], ru, fmaf(Jv[r], rv, acc[10 + r]));
                acc[14] = fmaf(ru, ru, fmaf(rv, rv, acc[14]));
            }
        }

        // all-reduce each partial across the wave (DPP + 2 shuffles)
#pragma unroll
        for (int k = 0; k < 15; ++k) acc[k] = wave_allreduce(acc[k]);

        const float costN = 0.5f * acc[14];

        // ---- accept / reject (wave-uniform, f32 like reference) ----
        bool accept;
        if (it == 0) {
            accept = true;
        } else {
            const float rel = (cost - costN) / mcc;
            const bool success = (rel >= 1e-3f) && (mcc > 0.0f);
            if (success) {
                const float q = 2.0f * rel - 1.0f;
                const float denom = fmaxf(1.0f - q * q * q, 1.0f / 3.0f);
                radius = fminf(radius / denom, 1e16f);
                dec = 2.0f;
            } else {
                radius = radius / dec;
                dec = dec * 2.0f;
            }
            accept = success;
        }
        if (accept) {
#pragma unroll
            for (int k = 0; k < 10; ++k) JtJ[k] = acc[k];
#pragma unroll
            for (int k = 0; k < 4; ++k) grad[k] = acc[10 + k];
            cost = costN;
            if (it > 0) { ax = ex; ay = ey; az = ez; ayaw = eyaw; }
        }

        if (it < NUM_ITER) {
            // LM-damped solve from accepted state
            float A[10], rhs[4], stf[4];
#pragma unroll
            for (int k = 0; k < 10; ++k) A[k] = JtJ[k];
            const float irad = 1.0f / radius;
            A[0] += fminf(fmaxf(JtJ[0], 1e-6f), 1e32f) * irad;
            A[4] += fminf(fmaxf(JtJ[4], 1e-6f), 1e32f) * irad;
            A[7] += fminf(fmaxf(JtJ[7], 1e-6f), 1e32f) * irad;
            A[9] += fminf(fmaxf(JtJ[9], 1e-6f), 1e32f) * irad;
#pragma unroll
            for (int r = 0; r < 4; ++r) rhs[r] = -grad[r];
            solve4_spd(A, rhs, stf);
            ex = ax + stf[0]; ey = ay + stf[1]; ez = az + stf[2]; eyaw = ayaw + stf[3];
            // model cost change with undamped JtJ
            const float s0 = stf[0], s1 = stf[1], s2 = stf[2], s3 = stf[3];
            const float Js0 = JtJ[0]*s0 + JtJ[1]*s1 + JtJ[2]*s2 + JtJ[3]*s3;
            const float Js1 = JtJ[1]*s0 + JtJ[4]*s1 + JtJ[5]*s2 + JtJ[6]*s3;
            const float Js2 = JtJ[2]*s0 + JtJ[5]*s1 + JtJ[7]*s2 + JtJ[8]*s3;
            const float Js3 = JtJ[3]*s0 + JtJ[6]*s1 + JtJ[8]*s2 + JtJ[9]*s3;
            mcc = -((s0*grad[0] + s1*grad[1] + s2*grad[2] + s3*grad[3]) +
                    0.5f * (s0*Js0 + s1*Js1 + s2*Js2 + s3*Js3));
            sn = __sinf(eyaw); cs = __cosf(eyaw);
        } else if (lane == 0) {
            // epilogue: pose_opt, cost, pose_opt + GN step
            float* out_pose = out;
            float* out_cost = out + (size_t)B * 4;
            float* out_plus = out + (size_t)B * 5;
            out_pose[(size_t)item * 4 + 0] = ax;
            out_pose[(size_t)item * 4 + 1] = ay;
            out_pose[(size_t)item * 4 + 2] = az;
            out_pose[(size_t)item * 4 + 3] = ayaw;
            out_cost[item] = cost;
            float A[10], rhs[4], stf[4];
#pragma unroll
            for (int k = 0; k < 10; ++k) A[k] = JtJ[k];
            A[0] += 1e-5f; A[4] += 1e-5f; A[7] += 1e-5f; A[9] += 1e-5f;
#pragma unroll
            for (int r = 0; r < 4; ++r) rhs[r] = -grad[r];
            solve4_spd(A, rhs, stf);
            out_plus[(size_t)item * 4 + 0] = ax + stf[0];
            out_plus[(size_t)item * 4 + 1] = ay + stf[1];
            out_plus[(size_t)item * 4 + 2] = az + stf[2];
            out_plus[(size_t)item * 4 + 3] = ayaw + stf[3];
        }
    }
}

extern "C" void kernel_launch(void* const* d_in, const int* in_sizes, int n_in,
                              void* d_out, int out_size, void* d_ws, size_t ws_size,
                              hipStream_t stream) {
    const float* x3d       = (const float*)d_in[0];
    const float* x2d       = (const float*)d_in[1];
    const float* w2d       = (const float*)d_in[2];
    const float* pose_init = (const float*)d_in[3];
    const float* cam       = (const float*)d_in[4];
    float* out = (float*)d_out;

    const int B = in_sizes[3] / 4;
    const int N = in_sizes[0] / (3 * B);
    const int grid = (B + 3) / 4;

    if (N == 512) {
        lm_kernel<8, true><<<grid, 256, 0, stream>>>(x3d, x2d, w2d, pose_init, cam, out, B, N);
    } else if (N == 256) {
        lm_kernel<4, true><<<grid, 256, 0, stream>>>(x3d, x2d, w2d, pose_init, cam, out, B, N);
    } else if (N <= 64) {
        lm_kernel<1, false><<<grid, 256, 0, stream>>>(x3d, x2d, w2d, pose_init, cam, out, B, N);
    } else if (N <= 128) {
        lm_kernel<2, false><<<grid, 256, 0, stream>>>(x3d, x2d, w2d, pose_init, cam, out, B, N);
    } else if (N <= 256) {
        lm_kernel<4, false><<<grid, 256, 0, stream>>>(x3d, x2d, w2d, pose_init, cam, out, B, N);
    } else if (N <= 512) {
        lm_kernel<8, false><<<grid, 256, 0, stream>>>(x3d, x2d, w2d, pose_init, cam, out, B, N);
    } else {
        lm_kernel<16, false><<<grid, 256, 0, stream>>>(x3d, x2d, w2d, pose_init, cam, out, B, N);
    }
}

// Round 6
// 138.921 us; speedup vs baseline: 4.0227x; 1.0986x over previous
//
#include <hip/hip_runtime.h>
#include <math.h>

#define NUM_ITER 10
#define Z_MIN 0.1f

__device__ inline float uniform_f(float v) {
    // item is wave-uniform -> force value into an SGPR
    return __int_as_float(__builtin_amdgcn_readfirstlane(__float_as_int(v)));
}

__device__ inline float fast_rcp(float x) {
    // raw v_rcp_f32 (~1 ulp) instead of the ~10-inst IEEE div sequence
    return __builtin_amdgcn_rcpf(x);
}

// Full-wave (64-lane) all-reduce of M values, stage-major for ILP.
// 4x DPP row_ror (within 16-lane rows) + ds_swizzle xor16 (within 32-lane
// halves) + ds_bpermute xor32 (hoisted byte address). Every lane ends with
// the full sum of each value.
template <int M>
__device__ inline void wave_allreduce_arr(float (&a)[M], int bp_addr) {
#pragma unroll
    for (int k = 0; k < M; ++k) {
        int t = __builtin_amdgcn_update_dpp(0, __float_as_int(a[k]), 0x121, 0xf, 0xf, true);
        a[k] += __int_as_float(t);  // ror:1
    }
#pragma unroll
    for (int k = 0; k < M; ++k) {
        int t = __builtin_amdgcn_update_dpp(0, __float_as_int(a[k]), 0x122, 0xf, 0xf, true);
        a[k] += __int_as_float(t);  // ror:2
    }
#pragma unroll
    for (int k = 0; k < M; ++k) {
        int t = __builtin_amdgcn_update_dpp(0, __float_as_int(a[k]), 0x124, 0xf, 0xf, true);
        a[k] += __int_as_float(t);  // ror:4
    }
#pragma unroll
    for (int k = 0; k < M; ++k) {
        int t = __builtin_amdgcn_update_dpp(0, __float_as_int(a[k]), 0x128, 0xf, 0xf, true);
        a[k] += __int_as_float(t);  // ror:8
    }
#pragma unroll
    for (int k = 0; k < M; ++k) {  // xor 16 within each 32-lane half
        int t = __builtin_amdgcn_ds_swizzle(__float_as_int(a[k]), 0x401F);
        a[k] += __int_as_float(t);
    }
#pragma unroll
    for (int k = 0; k < M; ++k) {  // xor 32 across halves
        int t = __builtin_amdgcn_ds_bpermute(bp_addr, __float_as_int(a[k]));
        a[k] += __int_as_float(t);
    }
}

// Branchless f32 LDL^T solve of 4x4 SPD system. t = upper-tri packed
// (00,01,02,03,11,12,13,22,23,33), solves A x = b.  Uses fast rcp.
__device__ inline void solve4_spd(const float t[10], const float b[4], float x[4]) {
    const float d0 = t[0];
    const float i0 = fast_rcp(d0);
    const float L10 = t[1] * i0, L20 = t[2] * i0, L30 = t[3] * i0;
    const float d1 = t[4] - L10 * t[1];
    const float i1 = fast_rcp(d1);
    const float L21 = (t[5] - L20 * t[1]) * i1;
    const float L31 = (t[6] - L30 * t[1]) * i1;
    const float d2 = t[7] - L20 * t[2] - L21 * L21 * d1;
    const float i2 = fast_rcp(d2);
    const float L32 = (t[8] - L30 * t[2] - L31 * L21 * d1) * i2;
    const float d3 = t[9] - L30 * t[3] - L31 * L31 * d1 - L32 * L32 * d2;
    const float i3 = fast_rcp(d3);
    const float y0 = b[0];
    const float y1 = b[1] - L10 * y0;
    const float y2 = b[2] - L20 * y0 - L21 * y1;
    const float y3 = b[3] - L30 * y0 - L31 * y1 - L32 * y2;
    const float z0 = y0 * i0, z1 = y1 * i1, z2 = y2 * i2, z3 = y3 * i3;
    x[3] = z3;
    x[2] = z2 - L32 * z3;
    x[1] = z1 - L21 * x[2] - L31 * x[3];
    x[0] = z0 - L10 * x[1] - L20 * x[2] - L30 * x[3];
}

// One wave (64 lanes) per batch item; 4 independent waves per 256-block.
// PPL points per lane held in VGPRs. NO min-waves launch-bounds arg: a
// register cap makes the allocator dump the point arrays to scratch
// (rounds 2-3: 0.9 GB scratch traffic). No LDS, no __syncthreads.
// EXACT: N == 64*PPL -> float4 loads of contiguous per-lane chunks.
template <int PPL, bool EXACT>
__global__ __launch_bounds__(256) void lm_kernel(
    const float* __restrict__ x3d, const float* __restrict__ x2d,
    const float* __restrict__ w2d, const float* __restrict__ pose_init,
    const float* __restrict__ K, float* __restrict__ out, int B, int N)
{
    const int wave = threadIdx.x >> 6;
    const int lane = threadIdx.x & 63;
    const int item = blockIdx.x * 4 + wave;
    if (item >= B) return;  // wave-uniform

    const int bp_addr = ((lane ^ 32) << 2);  // hoisted bpermute byte addr

    // ---- point data in registers (read exactly once) ----
    // f3: X,Y,Z   fw: wu,wv   fp: wu*u_obs, wv*v_obs (pre-multiplied targets)
    float f3[3 * PPL], fp[2 * PPL], fw[2 * PPL];
    if (EXACT) {
        const float4* p3 = reinterpret_cast<const float4*>(x3d + (size_t)item * N * 3) + lane * (3 * PPL / 4);
        const float4* p2 = reinterpret_cast<const float4*>(x2d + (size_t)item * N * 2) + lane * (2 * PPL / 4);
        const float4* pw = reinterpret_cast<const float4*>(w2d + (size_t)item * N * 2) + lane * (2 * PPL / 4);
#pragma unroll
        for (int i = 0; i < 3 * PPL / 4; ++i) {
            const float4 t = p3[i];
            f3[4 * i] = t.x; f3[4 * i + 1] = t.y; f3[4 * i + 2] = t.z; f3[4 * i + 3] = t.w;
        }
#pragma unroll
        for (int i = 0; i < 2 * PPL / 4; ++i) {
            const float4 t = pw[i];
            fw[4 * i] = t.x; fw[4 * i + 1] = t.y; fw[4 * i + 2] = t.z; fw[4 * i + 3] = t.w;
        }
#pragma unroll
        for (int i = 0; i < 2 * PPL / 4; ++i) {
            const float4 t = p2[i];
            fp[4 * i]     = t.x * fw[4 * i];
            fp[4 * i + 1] = t.y * fw[4 * i + 1];
            fp[4 * i + 2] = t.z * fw[4 * i + 2];
            fp[4 * i + 3] = t.w * fw[4 * i + 3];
        }
    } else {
        const float* x3b = x3d + (size_t)item * N * 3;
        const float* x2b = x2d + (size_t)item * N * 2;
        const float* w2b = w2d + (size_t)item * N * 2;
#pragma unroll
        for (int i = 0; i < PPL; ++i) {
            const int p = lane + i * 64;
            if (p < N) {
                f3[3 * i] = x3b[3 * p]; f3[3 * i + 1] = x3b[3 * p + 1]; f3[3 * i + 2] = x3b[3 * p + 2];
                fw[2 * i] = w2b[2 * p]; fw[2 * i + 1] = w2b[2 * p + 1];
                fp[2 * i] = x2b[2 * p] * fw[2 * i]; fp[2 * i + 1] = x2b[2 * p + 1] * fw[2 * i + 1];
            } else {
                f3[3 * i] = f3[3 * i + 1] = f3[3 * i + 2] = 0.f;
                fw[2 * i] = fw[2 * i + 1] = 0.f;
                fp[2 * i] = fp[2 * i + 1] = 0.f;
            }
        }
    }

    // ---- K: loop-invariant, wave-uniform -> SGPRs ----
    const float* Kb = K + (size_t)item * 9;
    const float K00 = uniform_f(Kb[0]), K01 = uniform_f(Kb[1]), K02 = uniform_f(Kb[2]);
    const float K10 = uniform_f(Kb[3]), K11 = uniform_f(Kb[4]), K12 = uniform_f(Kb[5]);
    const float K20 = uniform_f(Kb[6]), K21 = uniform_f(Kb[7]), K22 = uniform_f(Kb[8]);
    // pinhole form [[fx,0,cx],[0,fy,cy],[0,0,1]] -> big algebraic shortcuts
    const bool spec = (K01 == 0.f) && (K10 == 0.f) && (K20 == 0.f) &&
                      (K21 == 0.f) && (K22 == 1.f);

    // ---- wave-uniform control state (redundant on all 64 lanes, f32) ----
    float JtJ[10], grad[4];
    float cost = 0.f, radius = 30.0f, dec = 2.0f, mcc = 0.f;
#pragma unroll
    for (int k = 0; k < 10; ++k) JtJ[k] = 0.f;
#pragma unroll
    for (int k = 0; k < 4; ++k) grad[k] = 0.f;

    // accepted pose (a*) and currently-evaluated pose (e*)
    float ax = pose_init[(size_t)item * 4 + 0];
    float ay = pose_init[(size_t)item * 4 + 1];
    float az = pose_init[(size_t)item * 4 + 2];
    float ayaw = pose_init[(size_t)item * 4 + 3];
    float ex = ax, ey = ay, ez = az, eyaw = ayaw;
    float sn = __sinf(eyaw), cs = __cosf(eyaw);

    for (int it = 0; it <= NUM_ITER; ++it) {
        // acc: 0..9 JtJ upper-tri (00,01,02,03,11,12,13,22,23,33),
        //      10..13 grad, 14 = sum r^2
        float acc[15];

        if (spec) {
            // 14 active sums (JtJ01 == 0): s maps
            // 0:00 1:02 2:03 3:11 4:12 5:13 6:22 7:23 8:33 9..12:grad 13:r^2
            float s[14];
#pragma unroll
            for (int k = 0; k < 14; ++k) s[k] = 0.f;
#pragma unroll
            for (int i = 0; i < PPL; ++i) {
                const float X = f3[3 * i], Y = f3[3 * i + 1], Z = f3[3 * i + 2];
                const float px = fmaf(cs, X, fmaf(sn, Z, ex));
                const float py = Y + ey;
                const float pz = fmaf(-sn, X, fmaf(cs, Z, ez));
                const float nu = fmaf(K00, px, K02 * pz);
                const float nv = fmaf(K11, py, K12 * pz);
                const float zc = fmaxf(pz, Z_MIN);
                const float inv = fast_rcp(zc);
                const float gu = fw[2 * i] * inv, gv = fw[2 * i + 1] * inv;
                const float ru = fmaf(nu, gu, -fp[2 * i]);
                const float rv = fmaf(nv, gv, -fp[2 * i + 1]);
                const float u = nu * inv, v = nv * inv;
                const bool in = (pz > Z_MIN);
                const float ufl = in ? u : 0.f;
                const float vfl = in ? v : 0.f;
                const float a  = pz - ez;   // -s*X + c*Z
                const float bb = ex - px;   // -(c*X + s*Z)
                const float Ju0 = gu * K00;
                const float Jv1 = gv * K11;
                const float Ju2 = gu * (K02 - ufl);
                const float Jv2 = gv * (K12 - vfl);
                const float Ju3 = fmaf(Ju0, a, Ju2 * bb);
                const float Jv3 = Jv2 * bb;
                s[0]  = fmaf(Ju0, Ju0, s[0]);
                s[1]  = fmaf(Ju0, Ju2, s[1]);
                s[2]  = fmaf(Ju0, Ju3, s[2]);
                s[3]  = fmaf(Jv1, Jv1, s[3]);
                s[4]  = fmaf(Jv1, Jv2, s[4]);
                s[5]  = fmaf(Jv1, Jv3, s[5]);
                s[6]  = fmaf(Ju2, Ju2, fmaf(Jv2, Jv2, s[6]));
                s[7]  = fmaf(Ju2, Ju3, fmaf(Jv2, Jv3, s[7]));
                s[8]  = fmaf(Ju3, Ju3, fmaf(Jv3, Jv3, s[8]));
                s[9]  = fmaf(Ju0, ru, s[9]);
                s[10] = fmaf(Jv1, rv, s[10]);
                s[11] = fmaf(Ju2, ru, fmaf(Jv2, rv, s[11]));
                s[12] = fmaf(Ju3, ru, fmaf(Jv3, rv, s[12]));
                s[13] = fmaf(ru, ru, fmaf(rv, rv, s[13]));
            }
            wave_allreduce_arr<14>(s, bp_addr);
            acc[0] = s[0];  acc[1] = 0.f;  acc[2] = s[1];  acc[3] = s[2];
            acc[4] = s[3];  acc[5] = s[4]; acc[6] = s[5];  acc[7] = s[6];
            acc[8] = s[7];  acc[9] = s[8];
            acc[10] = s[9]; acc[11] = s[10]; acc[12] = s[11]; acc[13] = s[12];
            acc[14] = s[13];
        } else {
#pragma unroll
            for (int k = 0; k < 15; ++k) acc[k] = 0.f;
#pragma unroll
            for (int i = 0; i < PPL; ++i) {
                const float X = f3[3 * i], Y = f3[3 * i + 1], Z = f3[3 * i + 2];
                const float px = fmaf(cs, X, fmaf(sn, Z, ex));
                const float py = Y + ey;
                const float pz = fmaf(-sn, X, fmaf(cs, Z, ez));
                const float nu = fmaf(K00, px, fmaf(K01, py, K02 * pz));
                const float nv = fmaf(K10, px, fmaf(K11, py, K12 * pz));
                const float w  = fmaf(K20, px, fmaf(K21, py, K22 * pz));
                const float zc  = fmaxf(w, Z_MIN);
                const float inv = fast_rcp(zc);
                const float gu = fw[2 * i] * inv, gv = fw[2 * i + 1] * inv;
                const float ru = fmaf(nu, gu, -fp[2 * i]);
                const float rv = fmaf(nv, gv, -fp[2 * i + 1]);
                const float u = nu * inv, v = nv * inv;
                const float fl  = (w > Z_MIN) ? 1.f : 0.f;
                const float ufl = u * fl, vfl = v * fl;
                const float a  = pz - ez;
                const float bb = ex - px;
                const float dnu3 = fmaf(K00, a, K02 * bb);
                const float dnv3 = fmaf(K10, a, K12 * bb);
                const float dw3  = fmaf(K20, a, K22 * bb);
                float Ju[4], Jv[4];
                Ju[0] = gu * fmaf(-ufl, K20, K00);  Jv[0] = gv * fmaf(-vfl, K20, K10);
                Ju[1] = gu * fmaf(-ufl, K21, K01);  Jv[1] = gv * fmaf(-vfl, K21, K11);
                Ju[2] = gu * fmaf(-ufl, K22, K02);  Jv[2] = gv * fmaf(-vfl, K22, K12);
                Ju[3] = gu * fmaf(-ufl, dw3, dnu3); Jv[3] = gv * fmaf(-vfl, dw3, dnv3);
                int idx = 0;
#pragma unroll
                for (int r = 0; r < 4; ++r)
#pragma unroll
                    for (int c = r; c < 4; ++c) {
                        acc[idx] = fmaf(Ju[r], Ju[c], fmaf(Jv[r], Jv[c], acc[idx]));
                        ++idx;
                    }
#pragma unroll
                for (int r = 0; r < 4; ++r)
                    acc[10 + r] = fmaf(Ju[r], ru, fmaf(Jv[r], rv, acc[10 + r]));
                acc[14] = fmaf(ru, ru, fmaf(rv, rv, acc[14]));
            }
            wave_allreduce_arr<15>(acc, bp_addr);
        }

        const float costN = 0.5f * acc[14];

        // ---- accept / reject (wave-uniform, f32 like reference) ----
        bool accept;
        if (it == 0) {
            accept = true;
        } else {
            const float rel = (cost - costN) * fast_rcp(mcc);
            const bool success = (rel >= 1e-3f) && (mcc > 0.0f);
            if (success) {
                const float q = 2.0f * rel - 1.0f;
                const float denom = fmaxf(1.0f - q * q * q, 1.0f / 3.0f);
                radius = fminf(radius * fast_rcp(denom), 1e16f);
                dec = 2.0f;
            } else {
                radius = radius * fast_rcp(dec);  // dec = 2^k, rcp exact
                dec = dec * 2.0f;
            }
            accept = success;
        }
        if (accept) {
#pragma unroll
            for (int k = 0; k < 10; ++k) JtJ[k] = acc[k];
#pragma unroll
            for (int k = 0; k < 4; ++k) grad[k] = acc[10 + k];
            cost = costN;
            if (it > 0) { ax = ex; ay = ey; az = ez; ayaw = eyaw; }
        }

        if (it < NUM_ITER) {
            // LM-damped solve from accepted state
            float A[10], rhs[4], stf[4];
#pragma unroll
            for (int k = 0; k < 10; ++k) A[k] = JtJ[k];
            const float irad = fast_rcp(radius);
            A[0] += fminf(fmaxf(JtJ[0], 1e-6f), 1e32f) * irad;
            A[4] += fminf(fmaxf(JtJ[4], 1e-6f), 1e32f) * irad;
            A[7] += fminf(fmaxf(JtJ[7], 1e-6f), 1e32f) * irad;
            A[9] += fminf(fmaxf(JtJ[9], 1e-6f), 1e32f) * irad;
#pragma unroll
            for (int r = 0; r < 4; ++r) rhs[r] = -grad[r];
            solve4_spd(A, rhs, stf);
            ex = ax + stf[0]; ey = ay + stf[1]; ez = az + stf[2]; eyaw = ayaw + stf[3];
            // model cost change with undamped JtJ
            const float s0 = stf[0], s1 = stf[1], s2 = stf[2], s3 = stf[3];
            const float Js0 = JtJ[0]*s0 + JtJ[1]*s1 + JtJ[2]*s2 + JtJ[3]*s3;
            const float Js1 = JtJ[1]*s0 + JtJ[4]*s1 + JtJ[5]*s2 + JtJ[6]*s3;
            const float Js2 = JtJ[2]*s0 + JtJ[5]*s1 + JtJ[7]*s2 + JtJ[8]*s3;
            const float Js3 = JtJ[3]*s0 + JtJ[6]*s1 + JtJ[8]*s2 + JtJ[9]*s3;
            mcc = -((s0*grad[0] + s1*grad[1] + s2*grad[2] + s3*grad[3]) +
                    0.5f * (s0*Js0 + s1*Js1 + s2*Js2 + s3*Js3));
            sn = __sinf(eyaw); cs = __cosf(eyaw);
        } else if (lane == 0) {
            // epilogue: pose_opt, cost, pose_opt + GN step
            float* out_pose = out;
            float* out_cost = out + (size_t)B * 4;
            float* out_plus = out + (size_t)B * 5;
            out_pose[(size_t)item * 4 + 0] = ax;
            out_pose[(size_t)item * 4 + 1] = ay;
            out_pose[(size_t)item * 4 + 2] = az;
            out_pose[(size_t)item * 4 + 3] = ayaw;
            out_cost[item] = cost;
            float A[10], rhs[4], stf[4];
#pragma unroll
            for (int k = 0; k < 10; ++k) A[k] = JtJ[k];
            A[0] += 1e-5f; A[4] += 1e-5f; A[7] += 1e-5f; A[9] += 1e-5f;
#pragma unroll
            for (int r = 0; r < 4; ++r) rhs[r] = -grad[r];
            solve4_spd(A, rhs, stf);
            out_plus[(size_t)item * 4 + 0] = ax + stf[0];
            out_plus[(size_t)item * 4 + 1] = ay + stf[1];
            out_plus[(size_t)item * 4 + 2] = az + stf[2];
            out_plus[(size_t)item * 4 + 3] = ayaw + stf[3];
        }
    }
}

extern "C" void kernel_launch(void* const* d_in, const int* in_sizes, int n_in,
                              void* d_out, int out_size, void* d_ws, size_t ws_size,
                              hipStream_t stream) {
    const float* x3d       = (const float*)d_in[0];
    const float* x2d       = (const float*)d_in[1];
    const float* w2d       = (const float*)d_in[2];
    const float* pose_init = (const float*)d_in[3];
    const float* cam       = (const float*)d_in[4];
    float* out = (float*)d_out;

    const int B = in_sizes[3] / 4;
    const int N = in_sizes[0] / (3 * B);
    const int grid = (B + 3) / 4;

    if (N == 512) {
        lm_kernel<8, true><<<grid, 256, 0, stream>>>(x3d, x2d, w2d, pose_init, cam, out, B, N);
    } else if (N == 256) {
        lm_kernel<4, true><<<grid, 256, 0, stream>>>(x3d, x2d, w2d, pose_init, cam, out, B, N);
    } else if (N <= 64) {
        lm_kernel<1, false><<<grid, 256, 0, stream>>>(x3d, x2d, w2d, pose_init, cam, out, B, N);
    } else if (N <= 128) {
        lm_kernel<2, false><<<grid, 256, 0, stream>>>(x3d, x2d, w2d, pose_init, cam, out, B, N);
    } else if (N <= 256) {
        lm_kernel<4, false><<<grid, 256, 0, stream>>>(x3d, x2d, w2d, pose_init, cam, out, B, N);
    } else if (N <= 512) {
        lm_kernel<8, false><<<grid, 256, 0, stream>>>(x3d, x2d, w2d, pose_init, cam, out, B, N);
    } else {
        lm_kernel<16, false><<<grid, 256, 0, stream>>>(x3d, x2d, w2d, pose_init, cam, out, B, N);
    }
}

// Round 7
// 132.995 us; speedup vs baseline: 4.2019x; 1.0446x over previous
//
#include <hip/hip_runtime.h>
#include <math.h>

#define NUM_ITER 10
#define Z_MIN 0.1f

__device__ inline float uniform_f(float v) {
    // item is wave-uniform -> force value into an SGPR
    return __int_as_float(__builtin_amdgcn_readfirstlane(__float_as_int(v)));
}

__device__ inline float fast_rcp(float x) {
    // raw v_rcp_f32 (~1 ulp) instead of the ~10-inst IEEE div sequence
    return __builtin_amdgcn_rcpf(x);
}

// Full-wave (64-lane) all-reduce of M values, stage-major for ILP.
// 4x DPP row_ror (within 16-lane rows) + ds_swizzle xor16 (within 32-lane
// halves) + ds_bpermute xor32 (hoisted byte address). Every lane ends with
// the full sum of each value.
template <int M>
__device__ inline void wave_allreduce_arr(float (&a)[M], int bp_addr) {
#pragma unroll
    for (int k = 0; k < M; ++k) {
        int t = __builtin_amdgcn_update_dpp(0, __float_as_int(a[k]), 0x121, 0xf, 0xf, true);
        a[k] += __int_as_float(t);  // ror:1
    }
#pragma unroll
    for (int k = 0; k < M; ++k) {
        int t = __builtin_amdgcn_update_dpp(0, __float_as_int(a[k]), 0x122, 0xf, 0xf, true);
        a[k] += __int_as_float(t);  // ror:2
    }
#pragma unroll
    for (int k = 0; k < M; ++k) {
        int t = __builtin_amdgcn_update_dpp(0, __float_as_int(a[k]), 0x124, 0xf, 0xf, true);
        a[k] += __int_as_float(t);  // ror:4
    }
#pragma unroll
    for (int k = 0; k < M; ++k) {
        int t = __builtin_amdgcn_update_dpp(0, __float_as_int(a[k]), 0x128, 0xf, 0xf, true);
        a[k] += __int_as_float(t);  // ror:8
    }
#pragma unroll
    for (int k = 0; k < M; ++k) {  // xor 16 within each 32-lane half
        int t = __builtin_amdgcn_ds_swizzle(__float_as_int(a[k]), 0x401F);
        a[k] += __int_as_float(t);
    }
#pragma unroll
    for (int k = 0; k < M; ++k) {  // xor 32 across halves
        int t = __builtin_amdgcn_ds_bpermute(bp_addr, __float_as_int(a[k]));
        a[k] += __int_as_float(t);
    }
}

// Branchless f32 LDL^T solve of 4x4 SPD system. t = upper-tri packed
// (00,01,02,03,11,12,13,22,23,33), solves A x = b.  Uses fast rcp.
__device__ inline void solve4_spd(const float t[10], const float b[4], float x[4]) {
    const float d0 = t[0];
    const float i0 = fast_rcp(d0);
    const float L10 = t[1] * i0, L20 = t[2] * i0, L30 = t[3] * i0;
    const float d1 = t[4] - L10 * t[1];
    const float i1 = fast_rcp(d1);
    const float L21 = (t[5] - L20 * t[1]) * i1;
    const float L31 = (t[6] - L30 * t[1]) * i1;
    const float d2 = t[7] - L20 * t[2] - L21 * L21 * d1;
    const float i2 = fast_rcp(d2);
    const float L32 = (t[8] - L30 * t[2] - L31 * L21 * d1) * i2;
    const float d3 = t[9] - L30 * t[3] - L31 * L31 * d1 - L32 * L32 * d2;
    const float i3 = fast_rcp(d3);
    const float y0 = b[0];
    const float y1 = b[1] - L10 * y0;
    const float y2 = b[2] - L20 * y0 - L21 * y1;
    const float y3 = b[3] - L30 * y0 - L31 * y1 - L32 * y2;
    const float z0 = y0 * i0, z1 = y1 * i1, z2 = y2 * i2, z3 = y3 * i3;
    x[3] = z3;
    x[2] = z2 - L32 * z3;
    x[1] = z1 - L21 * x[2] - L31 * x[3];
    x[0] = z0 - L10 * x[1] - L20 * x[2] - L30 * x[3];
}

// One wave (64 lanes) per batch item; 4 independent waves per 256-block.
// PPL points per lane held in VGPRs. NO min-waves launch-bounds arg: a
// register cap makes the allocator dump the point arrays to scratch
// (rounds 2-3: 0.9 GB scratch traffic). No LDS, no __syncthreads.
// EXACT: N == 64*PPL -> float4 loads of contiguous per-lane chunks.
//
// Storage semantics (per point, arrays fA/fB):
//   spec (pinhole K): fA = (wu*fx, wv*fy), fB = (wu*(cx-u_obs), wv*(cy-v_obs))
//   generic:          fA = (wu, wv),       fB = (-wu*u_obs, -wv*v_obs)
template <int PPL, bool EXACT>
__global__ __launch_bounds__(256) void lm_kernel(
    const float* __restrict__ x3d, const float* __restrict__ x2d,
    const float* __restrict__ w2d, const float* __restrict__ pose_init,
    const float* __restrict__ K, float* __restrict__ out, int B, int N)
{
    const int wave = threadIdx.x >> 6;
    const int lane = threadIdx.x & 63;
    const int item = blockIdx.x * 4 + wave;
    if (item >= B) return;  // wave-uniform

    const int bp_addr = ((lane ^ 32) << 2);  // hoisted bpermute byte addr

    // ---- K: loop-invariant, wave-uniform -> SGPRs (needed before loads) ----
    const float* Kb = K + (size_t)item * 9;
    const float K00 = uniform_f(Kb[0]), K01 = uniform_f(Kb[1]), K02 = uniform_f(Kb[2]);
    const float K10 = uniform_f(Kb[3]), K11 = uniform_f(Kb[4]), K12 = uniform_f(Kb[5]);
    const float K20 = uniform_f(Kb[6]), K21 = uniform_f(Kb[7]), K22 = uniform_f(Kb[8]);
    // pinhole form [[fx,0,cx],[0,fy,cy],[0,0,1]] -> big algebraic shortcuts
    const bool spec = (K01 == 0.f) && (K10 == 0.f) && (K20 == 0.f) &&
                      (K21 == 0.f) && (K22 == 1.f);
    const float cxfx = K02 * fast_rcp(K00);  // out-of-range Ju2 factor
    const float cyfy = K12 * fast_rcp(K11);

    // ---- point data in registers (read exactly once) ----
    float f3[3 * PPL], fA[2 * PPL], fB[2 * PPL];
    if (EXACT) {
        const float4* p3 = reinterpret_cast<const float4*>(x3d + (size_t)item * N * 3) + lane * (3 * PPL / 4);
        const float4* p2 = reinterpret_cast<const float4*>(x2d + (size_t)item * N * 2) + lane * (2 * PPL / 4);
        const float4* pw = reinterpret_cast<const float4*>(w2d + (size_t)item * N * 2) + lane * (2 * PPL / 4);
#pragma unroll
        for (int i = 0; i < 3 * PPL / 4; ++i) {
            const float4 t = p3[i];
            f3[4 * i] = t.x; f3[4 * i + 1] = t.y; f3[4 * i + 2] = t.z; f3[4 * i + 3] = t.w;
        }
#pragma unroll
        for (int i = 0; i < 2 * PPL / 4; ++i) {
            const float4 tw = pw[i];
            const float4 to = p2[i];
            if (spec) {
                fA[4 * i]     = tw.x * K00;  fA[4 * i + 1] = tw.y * K11;
                fA[4 * i + 2] = tw.z * K00;  fA[4 * i + 3] = tw.w * K11;
                fB[4 * i]     = tw.x * (K02 - to.x);
                fB[4 * i + 1] = tw.y * (K12 - to.y);
                fB[4 * i + 2] = tw.z * (K02 - to.z);
                fB[4 * i + 3] = tw.w * (K12 - to.w);
            } else {
                fA[4 * i]     = tw.x;  fA[4 * i + 1] = tw.y;
                fA[4 * i + 2] = tw.z;  fA[4 * i + 3] = tw.w;
                fB[4 * i]     = -tw.x * to.x;  fB[4 * i + 1] = -tw.y * to.y;
                fB[4 * i + 2] = -tw.z * to.z;  fB[4 * i + 3] = -tw.w * to.w;
            }
        }
    } else {
        const float* x3b = x3d + (size_t)item * N * 3;
        const float* x2b = x2d + (size_t)item * N * 2;
        const float* w2b = w2d + (size_t)item * N * 2;
#pragma unroll
        for (int i = 0; i < PPL; ++i) {
            const int p = lane + i * 64;
            if (p < N) {
                f3[3 * i] = x3b[3 * p]; f3[3 * i + 1] = x3b[3 * p + 1]; f3[3 * i + 2] = x3b[3 * p + 2];
                const float wu = w2b[2 * p], wv = w2b[2 * p + 1];
                const float uo = x2b[2 * p], vo = x2b[2 * p + 1];
                if (spec) {
                    fA[2 * i] = wu * K00;          fA[2 * i + 1] = wv * K11;
                    fB[2 * i] = wu * (K02 - uo);   fB[2 * i + 1] = wv * (K12 - vo);
                } else {
                    fA[2 * i] = wu;        fA[2 * i + 1] = wv;
                    fB[2 * i] = -wu * uo;  fB[2 * i + 1] = -wv * vo;
                }
            } else {
                f3[3 * i] = f3[3 * i + 1] = f3[3 * i + 2] = 0.f;
                fA[2 * i] = fA[2 * i + 1] = 0.f;
                fB[2 * i] = fB[2 * i + 1] = 0.f;
            }
        }
    }

    // ---- wave-uniform control state (redundant on all 64 lanes, f32) ----
    float JtJ[10], grad[4];
    float cost = 0.f, radius = 30.0f, dec = 2.0f, mcc = 0.f;
#pragma unroll
    for (int k = 0; k < 10; ++k) JtJ[k] = 0.f;
#pragma unroll
    for (int k = 0; k < 4; ++k) grad[k] = 0.f;

    // accepted pose (a*) and currently-evaluated pose (e*)
    float ax = pose_init[(size_t)item * 4 + 0];
    float ay = pose_init[(size_t)item * 4 + 1];
    float az = pose_init[(size_t)item * 4 + 2];
    float ayaw = pose_init[(size_t)item * 4 + 3];
    float ex = ax, ey = ay, ez = az, eyaw = ayaw;
    float sn = __sinf(eyaw), cs = __cosf(eyaw);

    for (int it = 0; it <= NUM_ITER; ++it) {
        // acc: 0..9 JtJ upper-tri (00,01,02,03,11,12,13,22,23,33),
        //      10..13 grad, 14 = sum r^2
        float acc[15];

        if (spec) {
            // 14 active sums (JtJ01 == 0): s maps
            // 0:00 1:02 2:03 3:11 4:12 5:13 6:22 7:23 8:33 9..12:grad 13:r^2
            float s[14];
#pragma unroll
            for (int k = 0; k < 14; ++k) s[k] = 0.f;
#pragma unroll
            for (int i = 0; i < PPL; ++i) {
                const float X = f3[3 * i], Y = f3[3 * i + 1], Z = f3[3 * i + 2];
                const float px = fmaf(cs, X, fmaf(sn, Z, ex));
                const float py = Y + ey;
                const float pz = fmaf(-sn, X, fmaf(cs, Z, ez));
                const float zc = fmaxf(pz, Z_MIN);
                const float inv = fast_rcp(zc);
                const float alpha = px * inv;
                const float beta  = py * inv;
                const bool in = (pz > Z_MIN);
                const float t  = in ? -alpha : cxfx;   // Ju2 = Ju0 * t
                const float tv = in ? -beta  : cyfy;   // Jv2 = Jv1 * tv
                const float ru = fmaf(fA[2 * i],     alpha, fB[2 * i]);
                const float rv = fmaf(fA[2 * i + 1], beta,  fB[2 * i + 1]);
                const float Ju0 = fA[2 * i]     * inv;
                const float Jv1 = fA[2 * i + 1] * inv;
                const float Ju2 = Ju0 * t;
                const float Jv2 = Jv1 * tv;
                const float a  = pz - ez;   // -s*X + c*Z
                const float bb = ex - px;   // -(c*X + s*Z)
                const float q  = fmaf(t, bb, a);
                const float Ju3 = Ju0 * q;
                const float Jv3 = Jv2 * bb;
                s[0]  = fmaf(Ju0, Ju0, s[0]);
                s[1]  = fmaf(Ju0, Ju2, s[1]);
                s[2]  = fmaf(Ju0, Ju3, s[2]);
                s[3]  = fmaf(Jv1, Jv1, s[3]);
                s[4]  = fmaf(Jv1, Jv2, s[4]);
                s[5]  = fmaf(Jv1, Jv3, s[5]);
                s[6]  = fmaf(Ju2, Ju2, fmaf(Jv2, Jv2, s[6]));
                s[7]  = fmaf(Ju2, Ju3, fmaf(Jv2, Jv3, s[7]));
                s[8]  = fmaf(Ju3, Ju3, fmaf(Jv3, Jv3, s[8]));
                s[9]  = fmaf(Ju0, ru, s[9]);
                s[10] = fmaf(Jv1, rv, s[10]);
                s[11] = fmaf(Ju2, ru, fmaf(Jv2, rv, s[11]));
                s[12] = fmaf(Ju3, ru, fmaf(Jv3, rv, s[12]));
                s[13] = fmaf(ru, ru, fmaf(rv, rv, s[13]));
            }
            wave_allreduce_arr<14>(s, bp_addr);
            acc[0] = s[0];  acc[1] = 0.f;  acc[2] = s[1];  acc[3] = s[2];
            acc[4] = s[3];  acc[5] = s[4]; acc[6] = s[5];  acc[7] = s[6];
            acc[8] = s[7];  acc[9] = s[8];
            acc[10] = s[9]; acc[11] = s[10]; acc[12] = s[11]; acc[13] = s[12];
            acc[14] = s[13];
        } else {
#pragma unroll
            for (int k = 0; k < 15; ++k) acc[k] = 0.f;
#pragma unroll
            for (int i = 0; i < PPL; ++i) {
                const float X = f3[3 * i], Y = f3[3 * i + 1], Z = f3[3 * i + 2];
                const float px = fmaf(cs, X, fmaf(sn, Z, ex));
                const float py = Y + ey;
                const float pz = fmaf(-sn, X, fmaf(cs, Z, ez));
                const float nu = fmaf(K00, px, fmaf(K01, py, K02 * pz));
                const float nv = fmaf(K10, px, fmaf(K11, py, K12 * pz));
                const float w  = fmaf(K20, px, fmaf(K21, py, K22 * pz));
                const float zc  = fmaxf(w, Z_MIN);
                const float inv = fast_rcp(zc);
                const float gu = fA[2 * i] * inv, gv = fA[2 * i + 1] * inv;
                const float ru = fmaf(nu, gu, fB[2 * i]);
                const float rv = fmaf(nv, gv, fB[2 * i + 1]);
                const float u = nu * inv, v = nv * inv;
                const float fl  = (w > Z_MIN) ? 1.f : 0.f;
                const float ufl = u * fl, vfl = v * fl;
                const float a  = pz - ez;
                const float bb = ex - px;
                const float dnu3 = fmaf(K00, a, K02 * bb);
                const float dnv3 = fmaf(K10, a, K12 * bb);
                const float dw3  = fmaf(K20, a, K22 * bb);
                float Ju[4], Jv[4];
                Ju[0] = gu * fmaf(-ufl, K20, K00);  Jv[0] = gv * fmaf(-vfl, K20, K10);
                Ju[1] = gu * fmaf(-ufl, K21, K01);  Jv[1] = gv * fmaf(-vfl, K21, K11);
                Ju[2] = gu * fmaf(-ufl, K22, K02);  Jv[2] = gv * fmaf(-vfl, K22, K12);
                Ju[3] = gu * fmaf(-ufl, dw3, dnu3); Jv[3] = gv * fmaf(-vfl, dw3, dnv3);
                int idx = 0;
#pragma unroll
                for (int r = 0; r < 4; ++r)
#pragma unroll
                    for (int c = r; c < 4; ++c) {
                        acc[idx] = fmaf(Ju[r], Ju[c], fmaf(Jv[r], Jv[c], acc[idx]));
                        ++idx;
                    }
#pragma unroll
                for (int r = 0; r < 4; ++r)
                    acc[10 + r] = fmaf(Ju[r], ru, fmaf(Jv[r], rv, acc[10 + r]));
                acc[14] = fmaf(ru, ru, fmaf(rv, rv, acc[14]));
            }
            wave_allreduce_arr<15>(acc, bp_addr);
        }

        const float costN = 0.5f * acc[14];

        // ---- accept / reject (wave-uniform, f32 like reference) ----
        bool accept;
        if (it == 0) {
            accept = true;
        } else {
            const float rel = (cost - costN) * fast_rcp(mcc);
            const bool success = (rel >= 1e-3f) && (mcc > 0.0f);
            if (success) {
                const float q = 2.0f * rel - 1.0f;
                const float denom = fmaxf(1.0f - q * q * q, 1.0f / 3.0f);
                radius = fminf(radius * fast_rcp(denom), 1e16f);
                dec = 2.0f;
            } else {
                radius = radius * fast_rcp(dec);  // dec = 2^k, rcp exact
                dec = dec * 2.0f;
            }
            accept = success;
        }
        if (accept) {
#pragma unroll
            for (int k = 0; k < 10; ++k) JtJ[k] = acc[k];
#pragma unroll
            for (int k = 0; k < 4; ++k) grad[k] = acc[10 + k];
            cost = costN;
            if (it > 0) { ax = ex; ay = ey; az = ez; ayaw = eyaw; }
        }

        if (it < NUM_ITER) {
            // LM-damped solve from accepted state
            float A[10], rhs[4], stf[4];
#pragma unroll
            for (int k = 0; k < 10; ++k) A[k] = JtJ[k];
            const float irad = fast_rcp(radius);
            const float e0 = fminf(fmaxf(JtJ[0], 1e-6f), 1e32f) * irad;
            const float e1 = fminf(fmaxf(JtJ[4], 1e-6f), 1e32f) * irad;
            const float e2 = fminf(fmaxf(JtJ[7], 1e-6f), 1e32f) * irad;
            const float e3 = fminf(fmaxf(JtJ[9], 1e-6f), 1e32f) * irad;
            A[0] += e0; A[4] += e1; A[7] += e2; A[9] += e3;
#pragma unroll
            for (int r = 0; r < 4; ++r) rhs[r] = -grad[r];
            solve4_spd(A, rhs, stf);
            ex = ax + stf[0]; ey = ay + stf[1]; ez = az + stf[2]; eyaw = ayaw + stf[3];
            // model cost change via the damping identity:
            // (JtJ+D)s = -g  =>  s'JtJ s = -s'g - sum(e_i s_i^2)
            // mcc = -(s'g + 0.5 s'JtJ s) = 0.5*(sum(e_i s_i^2) - s'g)
            const float s0 = stf[0], s1 = stf[1], s2 = stf[2], s3 = stf[3];
            const float sg = s0 * grad[0] + s1 * grad[1] + s2 * grad[2] + s3 * grad[3];
            float sd = e0 * s0 * s0;
            sd = fmaf(e1 * s1, s1, sd);
            sd = fmaf(e2 * s2, s2, sd);
            sd = fmaf(e3 * s3, s3, sd);
            mcc = 0.5f * (sd - sg);
            sn = __sinf(eyaw); cs = __cosf(eyaw);
        } else if (lane == 0) {
            // epilogue: pose_opt, cost, pose_opt + GN step
            float* out_pose = out;
            float* out_cost = out + (size_t)B * 4;
            float* out_plus = out + (size_t)B * 5;
            out_pose[(size_t)item * 4 + 0] = ax;
            out_pose[(size_t)item * 4 + 1] = ay;
            out_pose[(size_t)item * 4 + 2] = az;
            out_pose[(size_t)item * 4 + 3] = ayaw;
            out_cost[item] = cost;
            float A[10], rhs[4], stf[4];
#pragma unroll
            for (int k = 0; k < 10; ++k) A[k] = JtJ[k];
            A[0] += 1e-5f; A[4] += 1e-5f; A[7] += 1e-5f; A[9] += 1e-5f;
#pragma unroll
            for (int r = 0; r < 4; ++r) rhs[r] = -grad[r];
            solve4_spd(A, rhs, stf);
            out_plus[(size_t)item * 4 + 0] = ax + stf[0];
            out_plus[(size_t)item * 4 + 1] = ay + stf[1];
            out_plus[(size_t)item * 4 + 2] = az + stf[2];
            out_plus[(size_t)item * 4 + 3] = ayaw + stf[3];
        }
    }
}

extern "C" void kernel_launch(void* const* d_in, const int* in_sizes, int n_in,
                              void* d_out, int out_size, void* d_ws, size_t ws_size,
                              hipStream_t stream) {
    const float* x3d       = (const float*)d_in[0];
    const float* x2d       = (const float*)d_in[1];
    const float* w2d       = (const float*)d_in[2];
    const float* pose_init = (const float*)d_in[3];
    const float* cam       = (const float*)d_in[4];
    float* out = (float*)d_out;

    const int B = in_sizes[3] / 4;
    const int N = in_sizes[0] / (3 * B);
    const int grid = (B + 3) / 4;

    if (N == 512) {
        lm_kernel<8, true><<<grid, 256, 0, stream>>>(x3d, x2d, w2d, pose_init, cam, out, B, N);
    } else if (N == 256) {
        lm_kernel<4, true><<<grid, 256, 0, stream>>>(x3d, x2d, w2d, pose_init, cam, out, B, N);
    } else if (N <= 64) {
        lm_kernel<1, false><<<grid, 256, 0, stream>>>(x3d, x2d, w2d, pose_init, cam, out, B, N);
    } else if (N <= 128) {
        lm_kernel<2, false><<<grid, 256, 0, stream>>>(x3d, x2d, w2d, pose_init, cam, out, B, N);
    } else if (N <= 256) {
        lm_kernel<4, false><<<grid, 256, 0, stream>>>(x3d, x2d, w2d, pose_init, cam, out, B, N);
    } else if (N <= 512) {
        lm_kernel<8, false><<<grid, 256, 0, stream>>>(x3d, x2d, w2d, pose_init, cam, out, B, N);
    } else {
        lm_kernel<16, false><<<grid, 256, 0, stream>>>(x3d, x2d, w2d, pose_init, cam, out, B, N);
    }
}

// Round 8
// 129.708 us; speedup vs baseline: 4.3084x; 1.0253x over previous
//
#include <hip/hip_runtime.h>
#include <math.h>

#define NUM_ITER 10
#define Z_MIN 0.1f

typedef float v2f __attribute__((ext_vector_type(2)));

__device__ inline float uniform_f(float v) {
    // item is wave-uniform -> force value into an SGPR
    return __int_as_float(__builtin_amdgcn_readfirstlane(__float_as_int(v)));
}

__device__ inline float fast_rcp(float x) {
    return __builtin_amdgcn_rcpf(x);
}

__device__ inline v2f fma2(v2f a, v2f b, v2f c) {
#if __has_builtin(__builtin_elementwise_fma)
    return __builtin_elementwise_fma(a, b, c);   // -> v_pk_fma_f32
#else
    v2f r; r.x = fmaf(a.x, b.x, c.x); r.y = fmaf(a.y, b.y, c.y); return r;
#endif
}

__device__ inline v2f max2(v2f a, v2f b) {
#if __has_builtin(__builtin_elementwise_max)
    return __builtin_elementwise_max(a, b);
#else
    v2f r; r.x = fmaxf(a.x, b.x); r.y = fmaxf(a.y, b.y); return r;
#endif
}

// Full-wave (64-lane) all-reduce of M values, stage-major for ILP.
// 4x DPP row_ror (within 16-lane rows) + ds_swizzle xor16 + ds_bpermute
// xor32 (hoisted byte address). Every lane ends with the full sum.
template <int M>
__device__ inline void wave_allreduce_arr(float (&a)[M], int bp_addr) {
#pragma unroll
    for (int k = 0; k < M; ++k) {
        int t = __builtin_amdgcn_update_dpp(0, __float_as_int(a[k]), 0x121, 0xf, 0xf, true);
        a[k] += __int_as_float(t);  // ror:1
    }
#pragma unroll
    for (int k = 0; k < M; ++k) {
        int t = __builtin_amdgcn_update_dpp(0, __float_as_int(a[k]), 0x122, 0xf, 0xf, true);
        a[k] += __int_as_float(t);  // ror:2
    }
#pragma unroll
    for (int k = 0; k < M; ++k) {
        int t = __builtin_amdgcn_update_dpp(0, __float_as_int(a[k]), 0x124, 0xf, 0xf, true);
        a[k] += __int_as_float(t);  // ror:4
    }
#pragma unroll
    for (int k = 0; k < M; ++k) {
        int t = __builtin_amdgcn_update_dpp(0, __float_as_int(a[k]), 0x128, 0xf, 0xf, true);
        a[k] += __int_as_float(t);  // ror:8
    }
#pragma unroll
    for (int k = 0; k < M; ++k) {  // xor 16 within each 32-lane half
        int t = __builtin_amdgcn_ds_swizzle(__float_as_int(a[k]), 0x401F);
        a[k] += __int_as_float(t);
    }
#pragma unroll
    for (int k = 0; k < M; ++k) {  // xor 32 across halves
        int t = __builtin_amdgcn_ds_bpermute(bp_addr, __float_as_int(a[k]));
        a[k] += __int_as_float(t);
    }
}

// Branchless f32 LDL^T solve of 4x4 SPD system. t = upper-tri packed
// (00,01,02,03,11,12,13,22,23,33), solves A x = b.  Uses fast rcp.
__device__ inline void solve4_spd(const float t[10], const float b[4], float x[4]) {
    const float d0 = t[0];
    const float i0 = fast_rcp(d0);
    const float L10 = t[1] * i0, L20 = t[2] * i0, L30 = t[3] * i0;
    const float d1 = t[4] - L10 * t[1];
    const float i1 = fast_rcp(d1);
    const float L21 = (t[5] - L20 * t[1]) * i1;
    const float L31 = (t[6] - L30 * t[1]) * i1;
    const float d2 = t[7] - L20 * t[2] - L21 * L21 * d1;
    const float i2 = fast_rcp(d2);
    const float L32 = (t[8] - L30 * t[2] - L31 * L21 * d1) * i2;
    const float d3 = t[9] - L30 * t[3] - L31 * L31 * d1 - L32 * L32 * d2;
    const float i3 = fast_rcp(d3);
    const float y0 = b[0];
    const float y1 = b[1] - L10 * y0;
    const float y2 = b[2] - L20 * y0 - L21 * y1;
    const float y3 = b[3] - L30 * y0 - L31 * y1 - L32 * y2;
    const float z0 = y0 * i0, z1 = y1 * i1, z2 = y2 * i2, z3 = y3 * i3;
    x[3] = z3;
    x[2] = z2 - L32 * z3;
    x[1] = z1 - L21 * x[2] - L31 * x[3];
    x[0] = z0 - L10 * x[1] - L20 * x[2] - L30 * x[3];
}

// One wave (64 lanes) per batch item; 4 independent waves per 256-block.
// Points held in VGPRs, processed in PAIRS with packed-f32 (v_pk_*) math.
// NO min-waves launch-bounds arg (reg cap -> wholesale scratch spill,
// rounds 2-3). No LDS, no __syncthreads.
// Storage (pairwise packed, pair j = points 2j,2j+1):
//   X2/Y2/Z2[j] = (val_2j, val_2j+1)
//   spec: Au2=(wu*fx), Av2=(wv*fy), Bu2=(wu*(cx-u_obs)), Bv2=(wv*(cy-v_obs))
//   generic: Au2=(wu), Av2=(wv), Bu2=(-wu*u_obs), Bv2=(-wv*v_obs)
template <int PPL, bool EXACT>
__global__ __launch_bounds__(256) void lm_kernel(
    const float* __restrict__ x3d, const float* __restrict__ x2d,
    const float* __restrict__ w2d, const float* __restrict__ pose_init,
    const float* __restrict__ K, float* __restrict__ out, int B, int N)
{
    static_assert(PPL % 2 == 0, "PPL must be even");
    constexpr int NP = PPL / 2;  // pairs per lane

    const int wave = threadIdx.x >> 6;
    const int lane = threadIdx.x & 63;
    const int item = blockIdx.x * 4 + wave;
    if (item >= B) return;  // wave-uniform

    const int bp_addr = ((lane ^ 32) << 2);  // hoisted bpermute byte addr

    // ---- K: loop-invariant, wave-uniform -> SGPRs ----
    const float* Kb = K + (size_t)item * 9;
    const float K00 = uniform_f(Kb[0]), K01 = uniform_f(Kb[1]), K02 = uniform_f(Kb[2]);
    const float K10 = uniform_f(Kb[3]), K11 = uniform_f(Kb[4]), K12 = uniform_f(Kb[5]);
    const float K20 = uniform_f(Kb[6]), K21 = uniform_f(Kb[7]), K22 = uniform_f(Kb[8]);
    const bool spec = (K01 == 0.f) && (K10 == 0.f) && (K20 == 0.f) &&
                      (K21 == 0.f) && (K22 == 1.f);
    const float cxfx = K02 * fast_rcp(K00);  // out-of-range Ju2 factor
    const float cyfy = K12 * fast_rcp(K11);

    // ---- point data in registers, pairwise packed (read exactly once) ----
    v2f X2[NP], Y2[NP], Z2[NP], Au2[NP], Av2[NP], Bu2[NP], Bv2[NP];
    if (EXACT) {
        const float4* p3 = reinterpret_cast<const float4*>(x3d + (size_t)item * N * 3) + lane * (3 * PPL / 4);
        const float4* p2 = reinterpret_cast<const float4*>(x2d + (size_t)item * N * 2) + lane * (2 * PPL / 4);
        const float4* pw = reinterpret_cast<const float4*>(w2d + (size_t)item * N * 2) + lane * (2 * PPL / 4);
        // x3d: 12 floats per 4 points -> 3 float4 per 2 pairs
        float f3[3 * PPL];
#pragma unroll
        for (int i = 0; i < 3 * PPL / 4; ++i) {
            const float4 t = p3[i];
            f3[4 * i] = t.x; f3[4 * i + 1] = t.y; f3[4 * i + 2] = t.z; f3[4 * i + 3] = t.w;
        }
#pragma unroll
        for (int j = 0; j < NP; ++j) {
            X2[j].x = f3[6 * j];     X2[j].y = f3[6 * j + 3];
            Y2[j].x = f3[6 * j + 1]; Y2[j].y = f3[6 * j + 4];
            Z2[j].x = f3[6 * j + 2]; Z2[j].y = f3[6 * j + 5];
        }
        // x2d/w2d: one float4 covers exactly one pair (u0,v0,u1,v1)
#pragma unroll
        for (int j = 0; j < NP; ++j) {
            const float4 tw = pw[j];
            const float4 to = p2[j];
            if (spec) {
                Au2[j].x = tw.x * K00;          Au2[j].y = tw.z * K00;
                Av2[j].x = tw.y * K11;          Av2[j].y = tw.w * K11;
                Bu2[j].x = tw.x * (K02 - to.x); Bu2[j].y = tw.z * (K02 - to.z);
                Bv2[j].x = tw.y * (K12 - to.y); Bv2[j].y = tw.w * (K12 - to.w);
            } else {
                Au2[j].x = tw.x;         Au2[j].y = tw.z;
                Av2[j].x = tw.y;         Av2[j].y = tw.w;
                Bu2[j].x = -tw.x * to.x; Bu2[j].y = -tw.z * to.z;
                Bv2[j].x = -tw.y * to.y; Bv2[j].y = -tw.w * to.w;
            }
        }
    } else {
        const float* x3b = x3d + (size_t)item * N * 3;
        const float* x2b = x2d + (size_t)item * N * 2;
        const float* w2b = w2d + (size_t)item * N * 2;
#pragma unroll
        for (int j = 0; j < NP; ++j) {
#pragma unroll
            for (int h = 0; h < 2; ++h) {
                const int p = lane + (2 * j + h) * 64;
                float X = 0.f, Y = 0.f, Z = 0.f, au = 0.f, av = 0.f, bu = 0.f, bv = 0.f;
                if (p < N) {
                    X = x3b[3 * p]; Y = x3b[3 * p + 1]; Z = x3b[3 * p + 2];
                    const float wu = w2b[2 * p], wv = w2b[2 * p + 1];
                    const float uo = x2b[2 * p], vo = x2b[2 * p + 1];
                    if (spec) {
                        au = wu * K00;        av = wv * K11;
                        bu = wu * (K02 - uo); bv = wv * (K12 - vo);
                    } else {
                        au = wu;       av = wv;
                        bu = -wu * uo; bv = -wv * vo;
                    }
                }
                if (h == 0) { X2[j].x = X; Y2[j].x = Y; Z2[j].x = Z;
                              Au2[j].x = au; Av2[j].x = av; Bu2[j].x = bu; Bv2[j].x = bv; }
                else        { X2[j].y = X; Y2[j].y = Y; Z2[j].y = Z;
                              Au2[j].y = au; Av2[j].y = av; Bu2[j].y = bu; Bv2[j].y = bv; }
            }
        }
    }

    // ---- wave-uniform control state (redundant on all 64 lanes, f32) ----
    float JtJ[10], grad[4];
    float cost = 0.f, radius = 30.0f, dec = 2.0f, mcc = 0.f;
#pragma unroll
    for (int k = 0; k < 10; ++k) JtJ[k] = 0.f;
#pragma unroll
    for (int k = 0; k < 4; ++k) grad[k] = 0.f;

    float ax = pose_init[(size_t)item * 4 + 0];
    float ay = pose_init[(size_t)item * 4 + 1];
    float az = pose_init[(size_t)item * 4 + 2];
    float ayaw = pose_init[(size_t)item * 4 + 3];
    float ex = ax, ey = ay, ez = az, eyaw = ayaw;
    float sn = __sinf(eyaw), cs = __cosf(eyaw);

    for (int it = 0; it <= NUM_ITER; ++it) {
        // acc: 0..9 JtJ upper-tri (00,01,02,03,11,12,13,22,23,33),
        //      10..13 grad, 14 = sum r^2
        float acc[15];

        if (spec) {
            // 14 packed accumulators; pair halves folded before wave-reduce.
            // map: 0:00 1:02 2:03 3:11 4:12 5:13 6:22 7:23 8:33 9..12:grad 13:r^2
            v2f s2[14];
#pragma unroll
            for (int k = 0; k < 14; ++k) s2[k] = (v2f)(0.f);
            const v2f cs2 = (v2f)(cs),  sn2 = (v2f)(sn);
            const v2f ex2 = (v2f)(ex),  ey2 = (v2f)(ey), ez2 = (v2f)(ez);
            const v2f zm2 = (v2f)(Z_MIN);
#pragma unroll
            for (int j = 0; j < NP; ++j) {
                const v2f X = X2[j], Y = Y2[j], Z = Z2[j];
                const v2f px = fma2(cs2, X, fma2(sn2, Z, ex2));
                const v2f py = Y + ey2;
                const v2f pz = fma2(-sn2, X, fma2(cs2, Z, ez2));
                const v2f zc = max2(pz, zm2);
                v2f inv; inv.x = fast_rcp(zc.x); inv.y = fast_rcp(zc.y);
                const v2f alpha = px * inv;
                const v2f beta  = py * inv;
                v2f t, tv;
                t.x  = (pz.x > Z_MIN) ? -alpha.x : cxfx;
                t.y  = (pz.y > Z_MIN) ? -alpha.y : cxfx;
                tv.x = (pz.x > Z_MIN) ? -beta.x  : cyfy;
                tv.y = (pz.y > Z_MIN) ? -beta.y  : cyfy;
                const v2f ru  = fma2(Au2[j], alpha, Bu2[j]);
                const v2f rv  = fma2(Av2[j], beta,  Bv2[j]);
                const v2f Ju0 = Au2[j] * inv;
                const v2f Jv1 = Av2[j] * inv;
                const v2f Ju2 = Ju0 * t;
                const v2f Jv2 = Jv1 * tv;
                const v2f a  = pz - ez2;   // -s*X + c*Z
                const v2f bb = ex2 - px;   // -(c*X + s*Z)
                const v2f q  = fma2(t, bb, a);
                const v2f Ju3 = Ju0 * q;
                const v2f Jv3 = Jv2 * bb;
                s2[0]  = fma2(Ju0, Ju0, s2[0]);
                s2[1]  = fma2(Ju0, Ju2, s2[1]);
                s2[2]  = fma2(Ju0, Ju3, s2[2]);
                s2[3]  = fma2(Jv1, Jv1, s2[3]);
                s2[4]  = fma2(Jv1, Jv2, s2[4]);
                s2[5]  = fma2(Jv1, Jv3, s2[5]);
                s2[6]  = fma2(Ju2, Ju2, fma2(Jv2, Jv2, s2[6]));
                s2[7]  = fma2(Ju2, Ju3, fma2(Jv2, Jv3, s2[7]));
                s2[8]  = fma2(Ju3, Ju3, fma2(Jv3, Jv3, s2[8]));
                s2[9]  = fma2(Ju0, ru, s2[9]);
                s2[10] = fma2(Jv1, rv, s2[10]);
                s2[11] = fma2(Ju2, ru, fma2(Jv2, rv, s2[11]));
                s2[12] = fma2(Ju3, ru, fma2(Jv3, rv, s2[12]));
                s2[13] = fma2(ru, ru, fma2(rv, rv, s2[13]));
            }
            float s[14];
#pragma unroll
            for (int k = 0; k < 14; ++k) s[k] = s2[k].x + s2[k].y;
            wave_allreduce_arr<14>(s, bp_addr);
            acc[0] = s[0];  acc[1] = 0.f;  acc[2] = s[1];  acc[3] = s[2];
            acc[4] = s[3];  acc[5] = s[4]; acc[6] = s[5];  acc[7] = s[6];
            acc[8] = s[7];  acc[9] = s[8];
            acc[10] = s[9]; acc[11] = s[10]; acc[12] = s[11]; acc[13] = s[12];
            acc[14] = s[13];
        } else {
#pragma unroll
            for (int k = 0; k < 15; ++k) acc[k] = 0.f;
#pragma unroll
            for (int j = 0; j < NP; ++j) {
#pragma unroll
                for (int h = 0; h < 2; ++h) {
                    const float X = h ? X2[j].y : X2[j].x;
                    const float Y = h ? Y2[j].y : Y2[j].x;
                    const float Z = h ? Z2[j].y : Z2[j].x;
                    const float au = h ? Au2[j].y : Au2[j].x;
                    const float av = h ? Av2[j].y : Av2[j].x;
                    const float bu = h ? Bu2[j].y : Bu2[j].x;
                    const float bv = h ? Bv2[j].y : Bv2[j].x;
                    const float px = fmaf(cs, X, fmaf(sn, Z, ex));
                    const float py = Y + ey;
                    const float pz = fmaf(-sn, X, fmaf(cs, Z, ez));
                    const float nu = fmaf(K00, px, fmaf(K01, py, K02 * pz));
                    const float nv = fmaf(K10, px, fmaf(K11, py, K12 * pz));
                    const float w  = fmaf(K20, px, fmaf(K21, py, K22 * pz));
                    const float zc  = fmaxf(w, Z_MIN);
                    const float inv = fast_rcp(zc);
                    const float gu = au * inv, gv = av * inv;
                    const float ru = fmaf(nu, gu, bu);
                    const float rv = fmaf(nv, gv, bv);
                    const float u = nu * inv, v = nv * inv;
                    const float fl  = (w > Z_MIN) ? 1.f : 0.f;
                    const float ufl = u * fl, vfl = v * fl;
                    const float a  = pz - ez;
                    const float bb = ex - px;
                    const float dnu3 = fmaf(K00, a, K02 * bb);
                    const float dnv3 = fmaf(K10, a, K12 * bb);
                    const float dw3  = fmaf(K20, a, K22 * bb);
                    float Ju[4], Jv[4];
                    Ju[0] = gu * fmaf(-ufl, K20, K00);  Jv[0] = gv * fmaf(-vfl, K20, K10);
                    Ju[1] = gu * fmaf(-ufl, K21, K01);  Jv[1] = gv * fmaf(-vfl, K21, K11);
                    Ju[2] = gu * fmaf(-ufl, K22, K02);  Jv[2] = gv * fmaf(-vfl, K22, K12);
                    Ju[3] = gu * fmaf(-ufl, dw3, dnu3); Jv[3] = gv * fmaf(-vfl, dw3, dnv3);
                    int idx = 0;
#pragma unroll
                    for (int r = 0; r < 4; ++r)
#pragma unroll
                        for (int c = r; c < 4; ++c) {
                            acc[idx] = fmaf(Ju[r], Ju[c], fmaf(Jv[r], Jv[c], acc[idx]));
                            ++idx;
                        }
#pragma unroll
                    for (int r = 0; r < 4; ++r)
                        acc[10 + r] = fmaf(Ju[r], ru, fmaf(Jv[r], rv, acc[10 + r]));
                    acc[14] = fmaf(ru, ru, fmaf(rv, rv, acc[14]));
                }
            }
            wave_allreduce_arr<15>(acc, bp_addr);
        }

        const float costN = 0.5f * acc[14];

        // ---- accept / reject (wave-uniform, f32 like reference) ----
        bool accept;
        if (it == 0) {
            accept = true;
        } else {
            const float rel = (cost - costN) * fast_rcp(mcc);
            const bool success = (rel >= 1e-3f) && (mcc > 0.0f);
            if (success) {
                const float q = 2.0f * rel - 1.0f;
                const float denom = fmaxf(1.0f - q * q * q, 1.0f / 3.0f);
                radius = fminf(radius * fast_rcp(denom), 1e16f);
                dec = 2.0f;
            } else {
                radius = radius * fast_rcp(dec);  // dec = 2^k, rcp exact
                dec = dec * 2.0f;
            }
            accept = success;
        }
        if (accept) {
#pragma unroll
            for (int k = 0; k < 10; ++k) JtJ[k] = acc[k];
#pragma unroll
            for (int k = 0; k < 4; ++k) grad[k] = acc[10 + k];
            cost = costN;
            if (it > 0) { ax = ex; ay = ey; az = ez; ayaw = eyaw; }
        }

        if (it < NUM_ITER) {
            // LM-damped solve from accepted state
            float A[10], rhs[4], stf[4];
#pragma unroll
            for (int k = 0; k < 10; ++k) A[k] = JtJ[k];
            const float irad = fast_rcp(radius);
            const float e0 = fminf(fmaxf(JtJ[0], 1e-6f), 1e32f) * irad;
            const float e1 = fminf(fmaxf(JtJ[4], 1e-6f), 1e32f) * irad;
            const float e2 = fminf(fmaxf(JtJ[7], 1e-6f), 1e32f) * irad;
            const float e3 = fminf(fmaxf(JtJ[9], 1e-6f), 1e32f) * irad;
            A[0] += e0; A[4] += e1; A[7] += e2; A[9] += e3;
#pragma unroll
            for (int r = 0; r < 4; ++r) rhs[r] = -grad[r];
            solve4_spd(A, rhs, stf);
            ex = ax + stf[0]; ey = ay + stf[1]; ez = az + stf[2]; eyaw = ayaw + stf[3];
            // mcc via damping identity: (JtJ+D)s=-g => s'JtJ s = -s'g - sum(e_i s_i^2)
            const float s0 = stf[0], s1 = stf[1], s2 = stf[2], s3 = stf[3];
            const float sg = s0 * grad[0] + s1 * grad[1] + s2 * grad[2] + s3 * grad[3];
            float sd = e0 * s0 * s0;
            sd = fmaf(e1 * s1, s1, sd);
            sd = fmaf(e2 * s2, s2, sd);
            sd = fmaf(e3 * s3, s3, sd);
            mcc = 0.5f * (sd - sg);
            sn = __sinf(eyaw); cs = __cosf(eyaw);
        } else if (lane == 0) {
            // epilogue: pose_opt, cost, pose_opt + GN step
            float* out_pose = out;
            float* out_cost = out + (size_t)B * 4;
            float* out_plus = out + (size_t)B * 5;
            out_pose[(size_t)item * 4 + 0] = ax;
            out_pose[(size_t)item * 4 + 1] = ay;
            out_pose[(size_t)item * 4 + 2] = az;
            out_pose[(size_t)item * 4 + 3] = ayaw;
            out_cost[item] = cost;
            float A[10], rhs[4], stf[4];
#pragma unroll
            for (int k = 0; k < 10; ++k) A[k] = JtJ[k];
            A[0] += 1e-5f; A[4] += 1e-5f; A[7] += 1e-5f; A[9] += 1e-5f;
#pragma unroll
            for (int r = 0; r < 4; ++r) rhs[r] = -grad[r];
            solve4_spd(A, rhs, stf);
            out_plus[(size_t)item * 4 + 0] = ax + stf[0];
            out_plus[(size_t)item * 4 + 1] = ay + stf[1];
            out_plus[(size_t)item * 4 + 2] = az + stf[2];
            out_plus[(size_t)item * 4 + 3] = ayaw + stf[3];
        }
    }
}

extern "C" void kernel_launch(void* const* d_in, const int* in_sizes, int n_in,
                              void* d_out, int out_size, void* d_ws, size_t ws_size,
                              hipStream_t stream) {
    const float* x3d       = (const float*)d_in[0];
    const float* x2d       = (const float*)d_in[1];
    const float* w2d       = (const float*)d_in[2];
    const float* pose_init = (const float*)d_in[3];
    const float* cam       = (const float*)d_in[4];
    float* out = (float*)d_out;

    const int B = in_sizes[3] / 4;
    const int N = in_sizes[0] / (3 * B);
    const int grid = (B + 3) / 4;

    if (N == 512) {
        lm_kernel<8, true><<<grid, 256, 0, stream>>>(x3d, x2d, w2d, pose_init, cam, out, B, N);
    } else if (N == 256) {
        lm_kernel<4, true><<<grid, 256, 0, stream>>>(x3d, x2d, w2d, pose_init, cam, out, B, N);
    } else if (N <= 128) {
        lm_kernel<2, false><<<grid, 256, 0, stream>>>(x3d, x2d, w2d, pose_init, cam, out, B, N);
    } else if (N <= 256) {
        lm_kernel<4, false><<<grid, 256, 0, stream>>>(x3d, x2d, w2d, pose_init, cam, out, B, N);
    } else if (N <= 512) {
        lm_kernel<8, false><<<grid, 256, 0, stream>>>(x3d, x2d, w2d, pose_init, cam, out, B, N);
    } else {
        lm_kernel<16, false><<<grid, 256, 0, stream>>>(x3d, x2d, w2d, pose_init, cam, out, B, N);
    }
}

// Round 9
// 126.258 us; speedup vs baseline: 4.4262x; 1.0273x over previous
//
#include <hip/hip_runtime.h>
#include <math.h>

#define NUM_ITER 10
#define Z_MIN 0.1f

typedef float v2f __attribute__((ext_vector_type(2)));

__device__ inline float uniform_f(float v) {
    // item is wave-uniform -> force value into an SGPR
    return __int_as_float(__builtin_amdgcn_readfirstlane(__float_as_int(v)));
}

__device__ inline float fast_rcp(float x) {
    return __builtin_amdgcn_rcpf(x);
}

__device__ inline v2f fma2(v2f a, v2f b, v2f c) {
#if __has_builtin(__builtin_elementwise_fma)
    return __builtin_elementwise_fma(a, b, c);   // -> v_pk_fma_f32
#else
    v2f r; r.x = fmaf(a.x, b.x, c.x); r.y = fmaf(a.y, b.y, c.y); return r;
#endif
}

__device__ inline v2f max2(v2f a, v2f b) {
#if __has_builtin(__builtin_elementwise_max)
    return __builtin_elementwise_max(a, b);
#else
    v2f r; r.x = fmaxf(a.x, b.x); r.y = fmaxf(a.y, b.y); return r;
#endif
}

// Full-wave (64-lane) reduce, ALL-VALU (no DS pipe, no lgkm waits):
// 4x DPP row_ror (each row of 16 ends with its row sum) +
// row_bcast15 (lanes 16-31 += row0, lanes 48-63 += row2) +
// row_bcast31 (lanes 32-63 += lanes0-31 sum) -> total in lanes 48-63;
// v_readlane lane 63 -> SGPR, uniform across the wave.
// Stage-major over M values for ILP.
template <int M>
__device__ inline void wave_reduce_uniform(float (&a)[M]) {
#pragma unroll
    for (int k = 0; k < M; ++k) {
        int t = __builtin_amdgcn_update_dpp(0, __float_as_int(a[k]), 0x121, 0xf, 0xf, true);
        a[k] += __int_as_float(t);  // ror:1
    }
#pragma unroll
    for (int k = 0; k < M; ++k) {
        int t = __builtin_amdgcn_update_dpp(0, __float_as_int(a[k]), 0x122, 0xf, 0xf, true);
        a[k] += __int_as_float(t);  // ror:2
    }
#pragma unroll
    for (int k = 0; k < M; ++k) {
        int t = __builtin_amdgcn_update_dpp(0, __float_as_int(a[k]), 0x124, 0xf, 0xf, true);
        a[k] += __int_as_float(t);  // ror:4
    }
#pragma unroll
    for (int k = 0; k < M; ++k) {
        int t = __builtin_amdgcn_update_dpp(0, __float_as_int(a[k]), 0x128, 0xf, 0xf, true);
        a[k] += __int_as_float(t);  // ror:8
    }
#pragma unroll
    for (int k = 0; k < M; ++k) {
        int t = __builtin_amdgcn_update_dpp(0, __float_as_int(a[k]), 0x142, 0xf, 0xf, true);
        a[k] += __int_as_float(t);  // row_bcast15
    }
#pragma unroll
    for (int k = 0; k < M; ++k) {
        int t = __builtin_amdgcn_update_dpp(0, __float_as_int(a[k]), 0x143, 0xf, 0xf, true);
        a[k] += __int_as_float(t);  // row_bcast31
    }
#pragma unroll
    for (int k = 0; k < M; ++k) {
        a[k] = __int_as_float(__builtin_amdgcn_readlane(__float_as_int(a[k]), 63));
    }
}

// Branchless f32 LDL^T solve of 4x4 SPD system. t = upper-tri packed
// (00,01,02,03,11,12,13,22,23,33), solves A x = b.  Uses fast rcp.
__device__ inline void solve4_spd(const float t[10], const float b[4], float x[4]) {
    const float d0 = t[0];
    const float i0 = fast_rcp(d0);
    const float L10 = t[1] * i0, L20 = t[2] * i0, L30 = t[3] * i0;
    const float d1 = t[4] - L10 * t[1];
    const float i1 = fast_rcp(d1);
    const float L21 = (t[5] - L20 * t[1]) * i1;
    const float L31 = (t[6] - L30 * t[1]) * i1;
    const float d2 = t[7] - L20 * t[2] - L21 * L21 * d1;
    const float i2 = fast_rcp(d2);
    const float L32 = (t[8] - L30 * t[2] - L31 * L21 * d1) * i2;
    const float d3 = t[9] - L30 * t[3] - L31 * L31 * d1 - L32 * L32 * d2;
    const float i3 = fast_rcp(d3);
    const float y0 = b[0];
    const float y1 = b[1] - L10 * y0;
    const float y2 = b[2] - L20 * y0 - L21 * y1;
    const float y3 = b[3] - L30 * y0 - L31 * y1 - L32 * y2;
    const float z0 = y0 * i0, z1 = y1 * i1, z2 = y2 * i2, z3 = y3 * i3;
    x[3] = z3;
    x[2] = z2 - L32 * z3;
    x[1] = z1 - L21 * x[2] - L31 * x[3];
    x[0] = z0 - L10 * x[1] - L20 * x[2] - L30 * x[3];
}

// One wave (64 lanes) per batch item; 4 independent waves per 256-block.
// Points held in VGPRs, processed in PAIRS with packed-f32 (v_pk_*) math.
// NO min-waves launch-bounds arg (reg cap -> wholesale scratch spill,
// rounds 2-3). No LDS, no __syncthreads, no DS-pipe ops at all.
template <int PPL, bool EXACT>
__global__ __launch_bounds__(256) void lm_kernel(
    const float* __restrict__ x3d, const float* __restrict__ x2d,
    const float* __restrict__ w2d, const float* __restrict__ pose_init,
    const float* __restrict__ K, float* __restrict__ out, int B, int N)
{
    static_assert(PPL % 2 == 0, "PPL must be even");
    constexpr int NP = PPL / 2;  // pairs per lane

    const int wave = threadIdx.x >> 6;
    const int lane = threadIdx.x & 63;
    const int item = blockIdx.x * 4 + wave;
    if (item >= B) return;  // wave-uniform

    // ---- K: loop-invariant, wave-uniform -> SGPRs ----
    const float* Kb = K + (size_t)item * 9;
    const float K00 = uniform_f(Kb[0]), K01 = uniform_f(Kb[1]), K02 = uniform_f(Kb[2]);
    const float K10 = uniform_f(Kb[3]), K11 = uniform_f(Kb[4]), K12 = uniform_f(Kb[5]);
    const float K20 = uniform_f(Kb[6]), K21 = uniform_f(Kb[7]), K22 = uniform_f(Kb[8]);
    const bool spec = (K01 == 0.f) && (K10 == 0.f) && (K20 == 0.f) &&
                      (K21 == 0.f) && (K22 == 1.f);
    const float cxfx = K02 * fast_rcp(K00);  // out-of-range Ju2 factor
    const float cyfy = K12 * fast_rcp(K11);

    // ---- point data in registers, pairwise packed (read exactly once) ----
    v2f X2[NP], Y2[NP], Z2[NP], Au2[NP], Av2[NP], Bu2[NP], Bv2[NP];
    if (EXACT) {
        const float4* p3 = reinterpret_cast<const float4*>(x3d + (size_t)item * N * 3) + lane * (3 * PPL / 4);
        const float4* p2 = reinterpret_cast<const float4*>(x2d + (size_t)item * N * 2) + lane * (2 * PPL / 4);
        const float4* pw = reinterpret_cast<const float4*>(w2d + (size_t)item * N * 2) + lane * (2 * PPL / 4);
        float f3[3 * PPL];
#pragma unroll
        for (int i = 0; i < 3 * PPL / 4; ++i) {
            const float4 t = p3[i];
            f3[4 * i] = t.x; f3[4 * i + 1] = t.y; f3[4 * i + 2] = t.z; f3[4 * i + 3] = t.w;
        }
#pragma unroll
        for (int j = 0; j < NP; ++j) {
            X2[j].x = f3[6 * j];     X2[j].y = f3[6 * j + 3];
            Y2[j].x = f3[6 * j + 1]; Y2[j].y = f3[6 * j + 4];
            Z2[j].x = f3[6 * j + 2]; Z2[j].y = f3[6 * j + 5];
        }
#pragma unroll
        for (int j = 0; j < NP; ++j) {
            const float4 tw = pw[j];
            const float4 to = p2[j];
            if (spec) {
                Au2[j].x = tw.x * K00;          Au2[j].y = tw.z * K00;
                Av2[j].x = tw.y * K11;          Av2[j].y = tw.w * K11;
                Bu2[j].x = tw.x * (K02 - to.x); Bu2[j].y = tw.z * (K02 - to.z);
                Bv2[j].x = tw.y * (K12 - to.y); Bv2[j].y = tw.w * (K12 - to.w);
            } else {
                Au2[j].x = tw.x;         Au2[j].y = tw.z;
                Av2[j].x = tw.y;         Av2[j].y = tw.w;
                Bu2[j].x = -tw.x * to.x; Bu2[j].y = -tw.z * to.z;
                Bv2[j].x = -tw.y * to.y; Bv2[j].y = -tw.w * to.w;
            }
        }
    } else {
        const float* x3b = x3d + (size_t)item * N * 3;
        const float* x2b = x2d + (size_t)item * N * 2;
        const float* w2b = w2d + (size_t)item * N * 2;
#pragma unroll
        for (int j = 0; j < NP; ++j) {
#pragma unroll
            for (int h = 0; h < 2; ++h) {
                const int p = lane + (2 * j + h) * 64;
                float X = 0.f, Y = 0.f, Z = 0.f, au = 0.f, av = 0.f, bu = 0.f, bv = 0.f;
                if (p < N) {
                    X = x3b[3 * p]; Y = x3b[3 * p + 1]; Z = x3b[3 * p + 2];
                    const float wu = w2b[2 * p], wv = w2b[2 * p + 1];
                    const float uo = x2b[2 * p], vo = x2b[2 * p + 1];
                    if (spec) {
                        au = wu * K00;        av = wv * K11;
                        bu = wu * (K02 - uo); bv = wv * (K12 - vo);
                    } else {
                        au = wu;       av = wv;
                        bu = -wu * uo; bv = -wv * vo;
                    }
                }
                if (h == 0) { X2[j].x = X; Y2[j].x = Y; Z2[j].x = Z;
                              Au2[j].x = au; Av2[j].x = av; Bu2[j].x = bu; Bv2[j].x = bv; }
                else        { X2[j].y = X; Y2[j].y = Y; Z2[j].y = Z;
                              Au2[j].y = au; Av2[j].y = av; Bu2[j].y = bu; Bv2[j].y = bv; }
            }
        }
    }

    // ---- wave-uniform control state (redundant on all 64 lanes, f32) ----
    float JtJ[10], grad[4];
    float cost = 0.f, radius = 30.0f, dec = 2.0f, mcc = 0.f;
#pragma unroll
    for (int k = 0; k < 10; ++k) JtJ[k] = 0.f;
#pragma unroll
    for (int k = 0; k < 4; ++k) grad[k] = 0.f;

    float ax = pose_init[(size_t)item * 4 + 0];
    float ay = pose_init[(size_t)item * 4 + 1];
    float az = pose_init[(size_t)item * 4 + 2];
    float ayaw = pose_init[(size_t)item * 4 + 3];
    float ex = ax, ey = ay, ez = az, eyaw = ayaw;
    float sn = __sinf(eyaw), cs = __cosf(eyaw);

    for (int it = 0; it <= NUM_ITER; ++it) {
        // acc: 0..9 JtJ upper-tri (00,01,02,03,11,12,13,22,23,33),
        //      10..13 grad, 14 = sum r^2
        float acc[15];

        if (spec) {
            // 14 packed accumulators; pair halves folded before wave-reduce.
            // map: 0:00 1:02 2:03 3:11 4:12 5:13 6:22 7:23 8:33 9..12:grad 13:r^2
            v2f s2[14];
#pragma unroll
            for (int k = 0; k < 14; ++k) s2[k] = (v2f)(0.f);
            const v2f cs2 = (v2f)(cs),  sn2 = (v2f)(sn);
            const v2f ex2 = (v2f)(ex),  ey2 = (v2f)(ey), ez2 = (v2f)(ez);
            const v2f zm2 = (v2f)(Z_MIN);
#pragma unroll
            for (int j = 0; j < NP; ++j) {
                const v2f X = X2[j], Y = Y2[j], Z = Z2[j];
                const v2f px = fma2(cs2, X, fma2(sn2, Z, ex2));
                const v2f py = Y + ey2;
                const v2f pz = fma2(-sn2, X, fma2(cs2, Z, ez2));
                const v2f zc = max2(pz, zm2);
                v2f inv; inv.x = fast_rcp(zc.x); inv.y = fast_rcp(zc.y);
                const v2f alpha = px * inv;
                const v2f beta  = py * inv;
                v2f t, tv;
                t.x  = (pz.x > Z_MIN) ? -alpha.x : cxfx;
                t.y  = (pz.y > Z_MIN) ? -alpha.y : cxfx;
                tv.x = (pz.x > Z_MIN) ? -beta.x  : cyfy;
                tv.y = (pz.y > Z_MIN) ? -beta.y  : cyfy;
                const v2f ru  = fma2(Au2[j], alpha, Bu2[j]);
                const v2f rv  = fma2(Av2[j], beta,  Bv2[j]);
                const v2f Ju0 = Au2[j] * inv;
                const v2f Jv1 = Av2[j] * inv;
                const v2f Ju2 = Ju0 * t;
                const v2f Jv2 = Jv1 * tv;
                const v2f a  = pz - ez2;   // -s*X + c*Z
                const v2f bb = ex2 - px;   // -(c*X + s*Z)
                const v2f q  = fma2(t, bb, a);
                const v2f Ju3 = Ju0 * q;
                const v2f Jv3 = Jv2 * bb;
                s2[0]  = fma2(Ju0, Ju0, s2[0]);
                s2[1]  = fma2(Ju0, Ju2, s2[1]);
                s2[2]  = fma2(Ju0, Ju3, s2[2]);
                s2[3]  = fma2(Jv1, Jv1, s2[3]);
                s2[4]  = fma2(Jv1, Jv2, s2[4]);
                s2[5]  = fma2(Jv1, Jv3, s2[5]);
                s2[6]  = fma2(Ju2, Ju2, fma2(Jv2, Jv2, s2[6]));
                s2[7]  = fma2(Ju2, Ju3, fma2(Jv2, Jv3, s2[7]));
                s2[8]  = fma2(Ju3, Ju3, fma2(Jv3, Jv3, s2[8]));
                s2[9]  = fma2(Ju0, ru, s2[9]);
                s2[10] = fma2(Jv1, rv, s2[10]);
                s2[11] = fma2(Ju2, ru, fma2(Jv2, rv, s2[11]));
                s2[12] = fma2(Ju3, ru, fma2(Jv3, rv, s2[12]));
                s2[13] = fma2(ru, ru, fma2(rv, rv, s2[13]));
            }
            float s[14];
#pragma unroll
            for (int k = 0; k < 14; ++k) s[k] = s2[k].x + s2[k].y;
            wave_reduce_uniform<14>(s);
            acc[0] = s[0];  acc[1] = 0.f;  acc[2] = s[1];  acc[3] = s[2];
            acc[4] = s[3];  acc[5] = s[4]; acc[6] = s[5];  acc[7] = s[6];
            acc[8] = s[7];  acc[9] = s[8];
            acc[10] = s[9]; acc[11] = s[10]; acc[12] = s[11]; acc[13] = s[12];
            acc[14] = s[13];
        } else {
#pragma unroll
            for (int k = 0; k < 15; ++k) acc[k] = 0.f;
#pragma unroll
            for (int j = 0; j < NP; ++j) {
#pragma unroll
                for (int h = 0; h < 2; ++h) {
                    const float X = h ? X2[j].y : X2[j].x;
                    const float Y = h ? Y2[j].y : Y2[j].x;
                    const float Z = h ? Z2[j].y : Z2[j].x;
                    const float au = h ? Au2[j].y : Au2[j].x;
                    const float av = h ? Av2[j].y : Av2[j].x;
                    const float bu = h ? Bu2[j].y : Bu2[j].x;
                    const float bv = h ? Bv2[j].y : Bv2[j].x;
                    const float px = fmaf(cs, X, fmaf(sn, Z, ex));
                    const float py = Y + ey;
                    const float pz = fmaf(-sn, X, fmaf(cs, Z, ez));
                    const float nu = fmaf(K00, px, fmaf(K01, py, K02 * pz));
                    const float nv = fmaf(K10, px, fmaf(K11, py, K12 * pz));
                    const float w  = fmaf(K20, px, fmaf(K21, py, K22 * pz));
                    const float zc  = fmaxf(w, Z_MIN);
                    const float inv = fast_rcp(zc);
                    const float gu = au * inv, gv = av * inv;
                    const float ru = fmaf(nu, gu, bu);
                    const float rv = fmaf(nv, gv, bv);
                    const float u = nu * inv, v = nv * inv;
                    const float fl  = (w > Z_MIN) ? 1.f : 0.f;
                    const float ufl = u * fl, vfl = v * fl;
                    const float a  = pz - ez;
                    const float bb = ex - px;
                    const float dnu3 = fmaf(K00, a, K02 * bb);
                    const float dnv3 = fmaf(K10, a, K12 * bb);
                    const float dw3  = fmaf(K20, a, K22 * bb);
                    float Ju[4], Jv[4];
                    Ju[0] = gu * fmaf(-ufl, K20, K00);  Jv[0] = gv * fmaf(-vfl, K20, K10);
                    Ju[1] = gu * fmaf(-ufl, K21, K01);  Jv[1] = gv * fmaf(-vfl, K21, K11);
                    Ju[2] = gu * fmaf(-ufl, K22, K02);  Jv[2] = gv * fmaf(-vfl, K22, K12);
                    Ju[3] = gu * fmaf(-ufl, dw3, dnu3); Jv[3] = gv * fmaf(-vfl, dw3, dnv3);
                    int idx = 0;
#pragma unroll
                    for (int r = 0; r < 4; ++r)
#pragma unroll
                        for (int c = r; c < 4; ++c) {
                            acc[idx] = fmaf(Ju[r], Ju[c], fmaf(Jv[r], Jv[c], acc[idx]));
                            ++idx;
                        }
#pragma unroll
                    for (int r = 0; r < 4; ++r)
                        acc[10 + r] = fmaf(Ju[r], ru, fmaf(Jv[r], rv, acc[10 + r]));
                    acc[14] = fmaf(ru, ru, fmaf(rv, rv, acc[14]));
                }
            }
            wave_reduce_uniform<15>(acc);
        }

        const float costN = 0.5f * acc[14];

        // ---- accept / reject (wave-uniform, f32 like reference) ----
        bool accept;
        if (it == 0) {
            accept = true;
        } else {
            const float rel = (cost - costN) * fast_rcp(mcc);
            const bool success = (rel >= 1e-3f) && (mcc > 0.0f);
            if (success) {
                const float q = 2.0f * rel - 1.0f;
                const float denom = fmaxf(1.0f - q * q * q, 1.0f / 3.0f);
                radius = fminf(radius * fast_rcp(denom), 1e16f);
                dec = 2.0f;
            } else {
                radius = radius * fast_rcp(dec);  // dec = 2^k, rcp exact
                dec = dec * 2.0f;
            }
            accept = success;
        }
        if (accept) {
#pragma unroll
            for (int k = 0; k < 10; ++k) JtJ[k] = acc[k];
#pragma unroll
            for (int k = 0; k < 4; ++k) grad[k] = acc[10 + k];
            cost = costN;
            if (it > 0) { ax = ex; ay = ey; az = ez; ayaw = eyaw; }
        }

        if (it < NUM_ITER) {
            // LM-damped solve from accepted state
            float A[10], rhs[4], stf[4];
#pragma unroll
            for (int k = 0; k < 10; ++k) A[k] = JtJ[k];
            const float irad = fast_rcp(radius);
            const float e0 = fminf(fmaxf(JtJ[0], 1e-6f), 1e32f) * irad;
            const float e1 = fminf(fmaxf(JtJ[4], 1e-6f), 1e32f) * irad;
            const float e2 = fminf(fmaxf(JtJ[7], 1e-6f), 1e32f) * irad;
            const float e3 = fminf(fmaxf(JtJ[9], 1e-6f), 1e32f) * irad;
            A[0] += e0; A[4] += e1; A[7] += e2; A[9] += e3;
#pragma unroll
            for (int r = 0; r < 4; ++r) rhs[r] = -grad[r];
            solve4_spd(A, rhs, stf);
            ex = ax + stf[0]; ey = ay + stf[1]; ez = az + stf[2]; eyaw = ayaw + stf[3];
            // mcc via damping identity: (JtJ+D)s=-g => s'JtJ s = -s'g - sum(e_i s_i^2)
            const float s0 = stf[0], s1 = stf[1], s2 = stf[2], s3 = stf[3];
            const float sg = s0 * grad[0] + s1 * grad[1] + s2 * grad[2] + s3 * grad[3];
            float sd = e0 * s0 * s0;
            sd = fmaf(e1 * s1, s1, sd);
            sd = fmaf(e2 * s2, s2, sd);
            sd = fmaf(e3 * s3, s3, sd);
            mcc = 0.5f * (sd - sg);
            sn = __sinf(eyaw); cs = __cosf(eyaw);
        } else if (lane == 0) {
            // epilogue: pose_opt, cost, pose_opt + GN step
            float* out_pose = out;
            float* out_cost = out + (size_t)B * 4;
            float* out_plus = out + (size_t)B * 5;
            out_pose[(size_t)item * 4 + 0] = ax;
            out_pose[(size_t)item * 4 + 1] = ay;
            out_pose[(size_t)item * 4 + 2] = az;
            out_pose[(size_t)item * 4 + 3] = ayaw;
            out_cost[item] = cost;
            float A[10], rhs[4], stf[4];
#pragma unroll
            for (int k = 0; k < 10; ++k) A[k] = JtJ[k];
            A[0] += 1e-5f; A[4] += 1e-5f; A[7] += 1e-5f; A[9] += 1e-5f;
#pragma unroll
            for (int r = 0; r < 4; ++r) rhs[r] = -grad[r];
            solve4_spd(A, rhs, stf);
            out_plus[(size_t)item * 4 + 0] = ax + stf[0];
            out_plus[(size_t)item * 4 + 1] = ay + stf[1];
            out_plus[(size_t)item * 4 + 2] = az + stf[2];
            out_plus[(size_t)item * 4 + 3] = ayaw + stf[3];
        }
    }
}

extern "C" void kernel_launch(void* const* d_in, const int* in_sizes, int n_in,
                              void* d_out, int out_size, void* d_ws, size_t ws_size,
                              hipStream_t stream) {
    const float* x3d       = (const float*)d_in[0];
    const float* x2d       = (const float*)d_in[1];
    const float* w2d       = (const float*)d_in[2];
    const float* pose_init = (const float*)d_in[3];
    const float* cam       = (const float*)d_in[4];
    float* out = (float*)d_out;

    const int B = in_sizes[3] / 4;
    const int N = in_sizes[0] / (3 * B);
    const int grid = (B + 3) / 4;

    if (N == 512) {
        lm_kernel<8, true><<<grid, 256, 0, stream>>>(x3d, x2d, w2d, pose_init, cam, out, B, N);
    } else if (N == 256) {
        lm_kernel<4, true><<<grid, 256, 0, stream>>>(x3d, x2d, w2d, pose_init, cam, out, B, N);
    } else if (N <= 128) {
        lm_kernel<2, false><<<grid, 256, 0, stream>>>(x3d, x2d, w2d, pose_init, cam, out, B, N);
    } else if (N <= 256) {
        lm_kernel<4, false><<<grid, 256, 0, stream>>>(x3d, x2d, w2d, pose_init, cam, out, B, N);
    } else if (N <= 512) {
        lm_kernel<8, false><<<grid, 256, 0, stream>>>(x3d, x2d, w2d, pose_init, cam, out, B, N);
    } else {
        lm_kernel<16, false><<<grid, 256, 0, stream>>>(x3d, x2d, w2d, pose_init, cam, out, B, N);
    }
}

// Round 10
// 125.921 us; speedup vs baseline: 4.4380x; 1.0027x over previous
//
#include <hip/hip_runtime.h>
#include <math.h>

#define NUM_ITER 10
#define Z_MIN 0.1f

typedef float v2f __attribute__((ext_vector_type(2)));

__device__ inline float uniform_f(float v) {
    // item is wave-uniform -> force value into an SGPR
    return __int_as_float(__builtin_amdgcn_readfirstlane(__float_as_int(v)));
}

__device__ inline float fast_rcp(float x) {
    return __builtin_amdgcn_rcpf(x);
}

__device__ inline v2f fma2(v2f a, v2f b, v2f c) {
#if __has_builtin(__builtin_elementwise_fma)
    return __builtin_elementwise_fma(a, b, c);   // -> v_pk_fma_f32
#else
    v2f r; r.x = fmaf(a.x, b.x, c.x); r.y = fmaf(a.y, b.y, c.y); return r;
#endif
}

__device__ inline v2f max2(v2f a, v2f b) {
#if __has_builtin(__builtin_elementwise_max)
    return __builtin_elementwise_max(a, b);
#else
    v2f r; r.x = fmaxf(a.x, b.x); r.y = fmaxf(a.y, b.y); return r;
#endif
}

// Full-wave (64-lane) reduce, ALL-VALU (no DS pipe, no lgkm waits):
// 4x DPP row_ror + row_bcast15 + row_bcast31 -> total in lanes 48-63;
// v_readlane lane 63 -> SGPR, uniform across the wave. Stage-major for ILP.
template <int M>
__device__ inline void wave_reduce_uniform(float (&a)[M]) {
#pragma unroll
    for (int k = 0; k < M; ++k) {
        int t = __builtin_amdgcn_update_dpp(0, __float_as_int(a[k]), 0x121, 0xf, 0xf, true);
        a[k] += __int_as_float(t);  // ror:1
    }
#pragma unroll
    for (int k = 0; k < M; ++k) {
        int t = __builtin_amdgcn_update_dpp(0, __float_as_int(a[k]), 0x122, 0xf, 0xf, true);
        a[k] += __int_as_float(t);  // ror:2
    }
#pragma unroll
    for (int k = 0; k < M; ++k) {
        int t = __builtin_amdgcn_update_dpp(0, __float_as_int(a[k]), 0x124, 0xf, 0xf, true);
        a[k] += __int_as_float(t);  // ror:4
    }
#pragma unroll
    for (int k = 0; k < M; ++k) {
        int t = __builtin_amdgcn_update_dpp(0, __float_as_int(a[k]), 0x128, 0xf, 0xf, true);
        a[k] += __int_as_float(t);  // ror:8
    }
#pragma unroll
    for (int k = 0; k < M; ++k) {
        int t = __builtin_amdgcn_update_dpp(0, __float_as_int(a[k]), 0x142, 0xf, 0xf, true);
        a[k] += __int_as_float(t);  // row_bcast15
    }
#pragma unroll
    for (int k = 0; k < M; ++k) {
        int t = __builtin_amdgcn_update_dpp(0, __float_as_int(a[k]), 0x143, 0xf, 0xf, true);
        a[k] += __int_as_float(t);  // row_bcast31
    }
#pragma unroll
    for (int k = 0; k < M; ++k) {
        a[k] = __int_as_float(__builtin_amdgcn_readlane(__float_as_int(a[k]), 63));
    }
}

// Branchless f32 LDL^T solve of 4x4 SPD system. t = upper-tri packed
// (00,01,02,03,11,12,13,22,23,33), solves A x = b.  Uses fast rcp.
__device__ inline void solve4_spd(const float t[10], const float b[4], float x[4]) {
    const float d0 = t[0];
    const float i0 = fast_rcp(d0);
    const float L10 = t[1] * i0, L20 = t[2] * i0, L30 = t[3] * i0;
    const float d1 = t[4] - L10 * t[1];
    const float i1 = fast_rcp(d1);
    const float L21 = (t[5] - L20 * t[1]) * i1;
    const float L31 = (t[6] - L30 * t[1]) * i1;
    const float d2 = t[7] - L20 * t[2] - L21 * L21 * d1;
    const float i2 = fast_rcp(d2);
    const float L32 = (t[8] - L30 * t[2] - L31 * L21 * d1) * i2;
    const float d3 = t[9] - L30 * t[3] - L31 * L31 * d1 - L32 * L32 * d2;
    const float i3 = fast_rcp(d3);
    const float y0 = b[0];
    const float y1 = b[1] - L10 * y0;
    const float y2 = b[2] - L20 * y0 - L21 * y1;
    const float y3 = b[3] - L30 * y0 - L31 * y1 - L32 * y2;
    const float z0 = y0 * i0, z1 = y1 * i1, z2 = y2 * i2, z3 = y3 * i3;
    x[3] = z3;
    x[2] = z2 - L32 * z3;
    x[1] = z1 - L21 * x[2] - L31 * x[3];
    x[0] = z0 - L10 * x[1] - L20 * x[2] - L30 * x[3];
}

// One wave (64 lanes) per batch item; 4 independent waves per 256-block.
// Points held in VGPRs, processed in PAIRS with packed-f32 math.
// NO min-waves launch-bounds arg (reg cap -> wholesale scratch spill,
// rounds 2-3). No LDS, no __syncthreads, no DS-pipe ops at all.
// Iteration loop is ROLLED (unroll(disable)): the ~400-inst body executed
// 11x from warm L1I; full unroll gives ~35 KB > 32 KB L1I -> fetch stalls
// (round-10 hypothesis for the unexplained 42% stall at 4 waves/SIMD).
template <int PPL, bool EXACT>
__global__ __launch_bounds__(256) void lm_kernel(
    const float* __restrict__ x3d, const float* __restrict__ x2d,
    const float* __restrict__ w2d, const float* __restrict__ pose_init,
    const float* __restrict__ K, float* __restrict__ out, int B, int N)
{
    static_assert(PPL % 2 == 0, "PPL must be even");
    constexpr int NP = PPL / 2;  // pairs per lane

    const int wave = threadIdx.x >> 6;
    const int lane = threadIdx.x & 63;
    const int item = blockIdx.x * 4 + wave;
    if (item >= B) return;  // wave-uniform

    // ---- K: loop-invariant, wave-uniform -> SGPRs ----
    const float* Kb = K + (size_t)item * 9;
    const float K00 = uniform_f(Kb[0]), K01 = uniform_f(Kb[1]), K02 = uniform_f(Kb[2]);
    const float K10 = uniform_f(Kb[3]), K11 = uniform_f(Kb[4]), K12 = uniform_f(Kb[5]);
    const float K20 = uniform_f(Kb[6]), K21 = uniform_f(Kb[7]), K22 = uniform_f(Kb[8]);
    const bool spec = (K01 == 0.f) && (K10 == 0.f) && (K20 == 0.f) &&
                      (K21 == 0.f) && (K22 == 1.f);
    const float cxfx = K02 * fast_rcp(K00);  // out-of-range Ju2 factor
    const float cyfy = K12 * fast_rcp(K11);

    // ---- point data in registers, pairwise packed (read exactly once) ----
    v2f X2[NP], Y2[NP], Z2[NP], Au2[NP], Av2[NP], Bu2[NP], Bv2[NP];
    if (EXACT) {
        const float4* p3 = reinterpret_cast<const float4*>(x3d + (size_t)item * N * 3) + lane * (3 * PPL / 4);
        const float4* p2 = reinterpret_cast<const float4*>(x2d + (size_t)item * N * 2) + lane * (2 * PPL / 4);
        const float4* pw = reinterpret_cast<const float4*>(w2d + (size_t)item * N * 2) + lane * (2 * PPL / 4);
        float f3[3 * PPL];
#pragma unroll
        for (int i = 0; i < 3 * PPL / 4; ++i) {
            const float4 t = p3[i];
            f3[4 * i] = t.x; f3[4 * i + 1] = t.y; f3[4 * i + 2] = t.z; f3[4 * i + 3] = t.w;
        }
#pragma unroll
        for (int j = 0; j < NP; ++j) {
            X2[j].x = f3[6 * j];     X2[j].y = f3[6 * j + 3];
            Y2[j].x = f3[6 * j + 1]; Y2[j].y = f3[6 * j + 4];
            Z2[j].x = f3[6 * j + 2]; Z2[j].y = f3[6 * j + 5];
        }
#pragma unroll
        for (int j = 0; j < NP; ++j) {
            const float4 tw = pw[j];
            const float4 to = p2[j];
            if (spec) {
                Au2[j].x = tw.x * K00;          Au2[j].y = tw.z * K00;
                Av2[j].x = tw.y * K11;          Av2[j].y = tw.w * K11;
                Bu2[j].x = tw.x * (K02 - to.x); Bu2[j].y = tw.z * (K02 - to.z);
                Bv2[j].x = tw.y * (K12 - to.y); Bv2[j].y = tw.w * (K12 - to.w);
            } else {
                Au2[j].x = tw.x;         Au2[j].y = tw.z;
                Av2[j].x = tw.y;         Av2[j].y = tw.w;
                Bu2[j].x = -tw.x * to.x; Bu2[j].y = -tw.z * to.z;
                Bv2[j].x = -tw.y * to.y; Bv2[j].y = -tw.w * to.w;
            }
        }
    } else {
        const float* x3b = x3d + (size_t)item * N * 3;
        const float* x2b = x2d + (size_t)item * N * 2;
        const float* w2b = w2d + (size_t)item * N * 2;
#pragma unroll
        for (int j = 0; j < NP; ++j) {
#pragma unroll
            for (int h = 0; h < 2; ++h) {
                const int p = lane + (2 * j + h) * 64;
                float X = 0.f, Y = 0.f, Z = 0.f, au = 0.f, av = 0.f, bu = 0.f, bv = 0.f;
                if (p < N) {
                    X = x3b[3 * p]; Y = x3b[3 * p + 1]; Z = x3b[3 * p + 2];
                    const float wu = w2b[2 * p], wv = w2b[2 * p + 1];
                    const float uo = x2b[2 * p], vo = x2b[2 * p + 1];
                    if (spec) {
                        au = wu * K00;        av = wv * K11;
                        bu = wu * (K02 - uo); bv = wv * (K12 - vo);
                    } else {
                        au = wu;       av = wv;
                        bu = -wu * uo; bv = -wv * vo;
                    }
                }
                if (h == 0) { X2[j].x = X; Y2[j].x = Y; Z2[j].x = Z;
                              Au2[j].x = au; Av2[j].x = av; Bu2[j].x = bu; Bv2[j].x = bv; }
                else        { X2[j].y = X; Y2[j].y = Y; Z2[j].y = Z;
                              Au2[j].y = au; Av2[j].y = av; Bu2[j].y = bu; Bv2[j].y = bv; }
            }
        }
    }

    // ---- wave-uniform control state (redundant on all 64 lanes, f32) ----
    float JtJ[10], grad[4];
    float cost = 0.f, radius = 30.0f, dec = 2.0f, mcc = 0.f;
#pragma unroll
    for (int k = 0; k < 10; ++k) JtJ[k] = 0.f;
#pragma unroll
    for (int k = 0; k < 4; ++k) grad[k] = 0.f;

    float ax = pose_init[(size_t)item * 4 + 0];
    float ay = pose_init[(size_t)item * 4 + 1];
    float az = pose_init[(size_t)item * 4 + 2];
    float ayaw = pose_init[(size_t)item * 4 + 3];
    float ex = ax, ey = ay, ez = az, eyaw = ayaw;
    float sn = __sinf(eyaw), cs = __cosf(eyaw);

    // ROLLED iteration loop: body stays resident in L1I across all 11 trips.
#pragma clang loop unroll(disable)
    for (int it = 0; it <= NUM_ITER; ++it) {
        // acc: 0..9 JtJ upper-tri (00,01,02,03,11,12,13,22,23,33),
        //      10..13 grad, 14 = sum r^2
        float acc[15];

        if (spec) {
            // 14 packed accumulators; pair halves folded before wave-reduce.
            // map: 0:00 1:02 2:03 3:11 4:12 5:13 6:22 7:23 8:33 9..12:grad 13:r^2
            v2f s2[14];
#pragma unroll
            for (int k = 0; k < 14; ++k) s2[k] = (v2f)(0.f);
            const v2f cs2 = (v2f)(cs),  sn2 = (v2f)(sn);
            const v2f ex2 = (v2f)(ex),  ey2 = (v2f)(ey), ez2 = (v2f)(ez);
            const v2f zm2 = (v2f)(Z_MIN);
#pragma unroll
            for (int j = 0; j < NP; ++j) {
                const v2f X = X2[j], Y = Y2[j], Z = Z2[j];
                const v2f px = fma2(cs2, X, fma2(sn2, Z, ex2));
                const v2f py = Y + ey2;
                const v2f pz = fma2(-sn2, X, fma2(cs2, Z, ez2));
                const v2f zc = max2(pz, zm2);
                v2f inv; inv.x = fast_rcp(zc.x); inv.y = fast_rcp(zc.y);
                const v2f alpha = px * inv;
                const v2f beta  = py * inv;
                v2f t, tv;
                t.x  = (pz.x > Z_MIN) ? -alpha.x : cxfx;
                t.y  = (pz.y > Z_MIN) ? -alpha.y : cxfx;
                tv.x = (pz.x > Z_MIN) ? -beta.x  : cyfy;
                tv.y = (pz.y > Z_MIN) ? -beta.y  : cyfy;
                const v2f ru  = fma2(Au2[j], alpha, Bu2[j]);
                const v2f rv  = fma2(Av2[j], beta,  Bv2[j]);
                const v2f Ju0 = Au2[j] * inv;
                const v2f Jv1 = Av2[j] * inv;
                const v2f Ju2 = Ju0 * t;
                const v2f Jv2 = Jv1 * tv;
                const v2f a  = pz - ez2;   // -s*X + c*Z
                const v2f bb = ex2 - px;   // -(c*X + s*Z)
                const v2f q  = fma2(t, bb, a);
                const v2f Ju3 = Ju0 * q;
                const v2f Jv3 = Jv2 * bb;
                s2[0]  = fma2(Ju0, Ju0, s2[0]);
                s2[1]  = fma2(Ju0, Ju2, s2[1]);
                s2[2]  = fma2(Ju0, Ju3, s2[2]);
                s2[3]  = fma2(Jv1, Jv1, s2[3]);
                s2[4]  = fma2(Jv1, Jv2, s2[4]);
                s2[5]  = fma2(Jv1, Jv3, s2[5]);
                s2[6]  = fma2(Ju2, Ju2, fma2(Jv2, Jv2, s2[6]));
                s2[7]  = fma2(Ju2, Ju3, fma2(Jv2, Jv3, s2[7]));
                s2[8]  = fma2(Ju3, Ju3, fma2(Jv3, Jv3, s2[8]));
                s2[9]  = fma2(Ju0, ru, s2[9]);
                s2[10] = fma2(Jv1, rv, s2[10]);
                s2[11] = fma2(Ju2, ru, fma2(Jv2, rv, s2[11]));
                s2[12] = fma2(Ju3, ru, fma2(Jv3, rv, s2[12]));
                s2[13] = fma2(ru, ru, fma2(rv, rv, s2[13]));
            }
            float s[14];
#pragma unroll
            for (int k = 0; k < 14; ++k) s[k] = s2[k].x + s2[k].y;
            wave_reduce_uniform<14>(s);
            acc[0] = s[0];  acc[1] = 0.f;  acc[2] = s[1];  acc[3] = s[2];
            acc[4] = s[3];  acc[5] = s[4]; acc[6] = s[5];  acc[7] = s[6];
            acc[8] = s[7];  acc[9] = s[8];
            acc[10] = s[9]; acc[11] = s[10]; acc[12] = s[11]; acc[13] = s[12];
            acc[14] = s[13];
        } else {
#pragma unroll
            for (int k = 0; k < 15; ++k) acc[k] = 0.f;
#pragma unroll
            for (int j = 0; j < NP; ++j) {
#pragma unroll
                for (int h = 0; h < 2; ++h) {
                    const float X = h ? X2[j].y : X2[j].x;
                    const float Y = h ? Y2[j].y : Y2[j].x;
                    const float Z = h ? Z2[j].y : Z2[j].x;
                    const float au = h ? Au2[j].y : Au2[j].x;
                    const float av = h ? Av2[j].y : Av2[j].x;
                    const float bu = h ? Bu2[j].y : Bu2[j].x;
                    const float bv = h ? Bv2[j].y : Bv2[j].x;
                    const float px = fmaf(cs, X, fmaf(sn, Z, ex));
                    const float py = Y + ey;
                    const float pz = fmaf(-sn, X, fmaf(cs, Z, ez));
                    const float nu = fmaf(K00, px, fmaf(K01, py, K02 * pz));
                    const float nv = fmaf(K10, px, fmaf(K11, py, K12 * pz));
                    const float w  = fmaf(K20, px, fmaf(K21, py, K22 * pz));
                    const float zc  = fmaxf(w, Z_MIN);
                    const float inv = fast_rcp(zc);
                    const float gu = au * inv, gv = av * inv;
                    const float ru = fmaf(nu, gu, bu);
                    const float rv = fmaf(nv, gv, bv);
                    const float u = nu * inv, v = nv * inv;
                    const float fl  = (w > Z_MIN) ? 1.f : 0.f;
                    const float ufl = u * fl, vfl = v * fl;
                    const float a  = pz - ez;
                    const float bb = ex - px;
                    const float dnu3 = fmaf(K00, a, K02 * bb);
                    const float dnv3 = fmaf(K10, a, K12 * bb);
                    const float dw3  = fmaf(K20, a, K22 * bb);
                    float Ju[4], Jv[4];
                    Ju[0] = gu * fmaf(-ufl, K20, K00);  Jv[0] = gv * fmaf(-vfl, K20, K10);
                    Ju[1] = gu * fmaf(-ufl, K21, K01);  Jv[1] = gv * fmaf(-vfl, K21, K11);
                    Ju[2] = gu * fmaf(-ufl, K22, K02);  Jv[2] = gv * fmaf(-vfl, K22, K12);
                    Ju[3] = gu * fmaf(-ufl, dw3, dnu3); Jv[3] = gv * fmaf(-vfl, dw3, dnv3);
                    int idx = 0;
#pragma unroll
                    for (int r = 0; r < 4; ++r)
#pragma unroll
                        for (int c = r; c < 4; ++c) {
                            acc[idx] = fmaf(Ju[r], Ju[c], fmaf(Jv[r], Jv[c], acc[idx]));
                            ++idx;
                        }
#pragma unroll
                    for (int r = 0; r < 4; ++r)
                        acc[10 + r] = fmaf(Ju[r], ru, fmaf(Jv[r], rv, acc[10 + r]));
                    acc[14] = fmaf(ru, ru, fmaf(rv, rv, acc[14]));
                }
            }
            wave_reduce_uniform<15>(acc);
        }

        const float costN = 0.5f * acc[14];

        // ---- accept / reject (wave-uniform, f32 like reference) ----
        bool accept;
        if (it == 0) {
            accept = true;
        } else {
            const float rel = (cost - costN) * fast_rcp(mcc);
            const bool success = (rel >= 1e-3f) && (mcc > 0.0f);
            if (success) {
                const float q = 2.0f * rel - 1.0f;
                const float denom = fmaxf(1.0f - q * q * q, 1.0f / 3.0f);
                radius = fminf(radius * fast_rcp(denom), 1e16f);
                dec = 2.0f;
            } else {
                radius = radius * fast_rcp(dec);  // dec = 2^k, rcp exact
                dec = dec * 2.0f;
            }
            accept = success;
        }
        if (accept) {
#pragma unroll
            for (int k = 0; k < 10; ++k) JtJ[k] = acc[k];
#pragma unroll
            for (int k = 0; k < 4; ++k) grad[k] = acc[10 + k];
            cost = costN;
            if (it > 0) { ax = ex; ay = ey; az = ez; ayaw = eyaw; }
        }

        if (it < NUM_ITER) {
            // LM-damped solve from accepted state
            float A[10], rhs[4], stf[4];
#pragma unroll
            for (int k = 0; k < 10; ++k) A[k] = JtJ[k];
            const float irad = fast_rcp(radius);
            const float e0 = fminf(fmaxf(JtJ[0], 1e-6f), 1e32f) * irad;
            const float e1 = fminf(fmaxf(JtJ[4], 1e-6f), 1e32f) * irad;
            const float e2 = fminf(fmaxf(JtJ[7], 1e-6f), 1e32f) * irad;
            const float e3 = fminf(fmaxf(JtJ[9], 1e-6f), 1e32f) * irad;
            A[0] += e0; A[4] += e1; A[7] += e2; A[9] += e3;
#pragma unroll
            for (int r = 0; r < 4; ++r) rhs[r] = -grad[r];
            solve4_spd(A, rhs, stf);
            ex = ax + stf[0]; ey = ay + stf[1]; ez = az + stf[2]; eyaw = ayaw + stf[3];
            // mcc via damping identity: (JtJ+D)s=-g => s'JtJ s = -s'g - sum(e_i s_i^2)
            const float s0 = stf[0], s1 = stf[1], s2 = stf[2], s3 = stf[3];
            const float sg = s0 * grad[0] + s1 * grad[1] + s2 * grad[2] + s3 * grad[3];
            float sd = e0 * s0 * s0;
            sd = fmaf(e1 * s1, s1, sd);
            sd = fmaf(e2 * s2, s2, sd);
            sd = fmaf(e3 * s3, s3, sd);
            mcc = 0.5f * (sd - sg);
            sn = __sinf(eyaw); cs = __cosf(eyaw);
        } else if (lane == 0) {
            // epilogue: pose_opt, cost, pose_opt + GN step
            float* out_pose = out;
            float* out_cost = out + (size_t)B * 4;
            float* out_plus = out + (size_t)B * 5;
            out_pose[(size_t)item * 4 + 0] = ax;
            out_pose[(size_t)item * 4 + 1] = ay;
            out_pose[(size_t)item * 4 + 2] = az;
            out_pose[(size_t)item * 4 + 3] = ayaw;
            out_cost[item] = cost;
            float A[10], rhs[4], stf[4];
#pragma unroll
            for (int k = 0; k < 10; ++k) A[k] = JtJ[k];
            A[0] += 1e-5f; A[4] += 1e-5f; A[7] += 1e-5f; A[9] += 1e-5f;
#pragma unroll
            for (int r = 0; r < 4; ++r) rhs[r] = -grad[r];
            solve4_spd(A, rhs, stf);
            out_plus[(size_t)item * 4 + 0] = ax + stf[0];
            out_plus[(size_t)item * 4 + 1] = ay + stf[1];
            out_plus[(size_t)item * 4 + 2] = az + stf[2];
            out_plus[(size_t)item * 4 + 3] = ayaw + stf[3];
        }
    }
}

extern "C" void kernel_launch(void* const* d_in, const int* in_sizes, int n_in,
                              void* d_out, int out_size, void* d_ws, size_t ws_size,
                              hipStream_t stream) {
    const float* x3d       = (const float*)d_in[0];
    const float* x2d       = (const float*)d_in[1];
    const float* w2d       = (const float*)d_in[2];
    const float* pose_init = (const float*)d_in[3];
    const float* cam       = (const float*)d_in[4];
    float* out = (float*)d_out;

    const int B = in_sizes[3] / 4;
    const int N = in_sizes[0] / (3 * B);
    const int grid = (B + 3) / 4;

    if (N == 512) {
        lm_kernel<8, true><<<grid, 256, 0, stream>>>(x3d, x2d, w2d, pose_init, cam, out, B, N);
    } else if (N == 256) {
        lm_kernel<4, true><<<grid, 256, 0, stream>>>(x3d, x2d, w2d, pose_init, cam, out, B, N);
    } else if (N <= 128) {
        lm_kernel<2, false><<<grid, 256, 0, stream>>>(x3d, x2d, w2d, pose_init, cam, out, B, N);
    } else if (N <= 256) {
        lm_kernel<4, false><<<grid, 256, 0, stream>>>(x3d, x2d, w2d, pose_init, cam, out, B, N);
    } else if (N <= 512) {
        lm_kernel<8, false><<<grid, 256, 0, stream>>>(x3d, x2d, w2d, pose_init, cam, out, B, N);
    } else {
        lm_kernel<16, false><<<grid, 256, 0, stream>>>(x3d, x2d, w2d, pose_init, cam, out, B, N);
    }
}